// Round 2
// baseline (400.100 us; speedup 1.0000x reference)
//
#include <hip/hip_runtime.h>
#include <hip/hip_bf16.h>

#define SS 2048
#define DD 2048
#define HH 16
#define HDIM 128

typedef unsigned short u16;
typedef __attribute__((ext_vector_type(8))) short bf16x8;
typedef __attribute__((ext_vector_type(4))) float f32x4;
typedef __attribute__((ext_vector_type(16))) float f32x16;
typedef __attribute__((ext_vector_type(4))) unsigned short u16x4;
typedef __attribute__((ext_vector_type(4))) int i32x4;
typedef __attribute__((ext_vector_type(4))) unsigned int u32x4;

__device__ __forceinline__ u16 f2bf(float f){
  unsigned u = __float_as_uint(f);
  u += 0x7FFFu + ((u >> 16) & 1u);
  return (u16)(u >> 16);
}

__device__ __forceinline__ void gload_lds16(const void* g, void* l){
  __builtin_amdgcn_global_load_lds(
      (const __attribute__((address_space(1))) void*)g,
      (__attribute__((address_space(3))) void*)l, 16, 0, 0);
}

__device__ __forceinline__ f32x4 mfma16(bf16x8 a, bf16x8 b, f32x4 c){
  return __builtin_amdgcn_mfma_f32_16x16x32_bf16(a, b, c, 0, 0, 0);
}
__device__ __forceinline__ f32x16 mfma32(bf16x8 a, bf16x8 b, f32x16 c){
  return __builtin_amdgcn_mfma_f32_32x32x16_bf16(a, b, c, 0, 0, 0);
}

// ---------------- K1: fused embedding add + LayerNorm ----------------
__global__ __launch_bounds__(256) void k_embed_ln(
    const float* __restrict__ br, const int* __restrict__ cat,
    const int* __restrict__ cse, const int* __restrict__ cmb,
    const float* __restrict__ cat_e, const float* __restrict__ case_e,
    const float* __restrict__ comb_e, const float* __restrict__ lg,
    const float* __restrict__ lb, float* __restrict__ xn32, u16* __restrict__ xn16)
{
  const int s = blockIdx.x, t = threadIdx.x;
  const int lane = t & 63, wave = t >> 6;
  const int c0 = cat[s], c1 = cse[s], c2 = cmb[s];
  const f32x4* pb = (const f32x4*)(br + (size_t)s * DD);
  const f32x4* e0 = (const f32x4*)(cat_e + (size_t)c0 * DD);
  const f32x4* e1 = (const f32x4*)(case_e + (size_t)c1 * DD);
  const f32x4* e2 = (const f32x4*)(comb_e + (size_t)c2 * DD);
  f32x4 xa = pb[t] + e0[t] + e1[t] + e2[t];
  f32x4 xb = pb[t+256] + e0[t+256] + e1[t+256] + e2[t+256];
  float s1 = 0.f, s2 = 0.f;
#pragma unroll
  for (int i = 0; i < 4; ++i){ s1 += xa[i] + xb[i]; s2 += xa[i]*xa[i] + xb[i]*xb[i]; }
#pragma unroll
  for (int off = 32; off > 0; off >>= 1){ s1 += __shfl_down(s1, off); s2 += __shfl_down(s2, off); }
  __shared__ float red[8];
  if (lane == 0){ red[wave*2] = s1; red[wave*2+1] = s2; }
  __syncthreads();
  const float t1 = red[0]+red[2]+red[4]+red[6];
  const float t2 = red[1]+red[3]+red[5]+red[7];
  const float mean = t1 * (1.0f/DD);
  const float var  = t2 * (1.0f/DD) - mean*mean;
  const float rstd = rsqrtf(var + 1e-5f);
  const f32x4* g4 = (const f32x4*)lg;
  const f32x4* b4 = (const f32x4*)lb;
  f32x4 ga = g4[t], gb = g4[t+256], ba = b4[t], bb = b4[t+256];
  f32x4 ya, yb; u16x4 ha, hb;
#pragma unroll
  for (int i = 0; i < 4; ++i){
    ya[i] = (xa[i]-mean)*rstd*ga[i] + ba[i];
    yb[i] = (xb[i]-mean)*rstd*gb[i] + bb[i];
    ha[i] = f2bf(ya[i]); hb[i] = f2bf(yb[i]);
  }
  ((f32x4*)(xn32 + (size_t)s*DD))[t]     = ya;
  ((f32x4*)(xn32 + (size_t)s*DD))[t+256] = yb;
  ((u16x4*)(xn16 + (size_t)s*DD))[t]     = ha;
  ((u16x4*)(xn16 + (size_t)s*DD))[t+256] = hb;
}

// ---------------- K2: f32 -> bf16 convert (vectorized, grid-stride) ----------------
__global__ __launch_bounds__(256) void k_f32_to_bf16(
    const float* __restrict__ in, u16* __restrict__ out, int n4)
{
  int i = blockIdx.x * blockDim.x + threadIdx.x;
  const int stride = gridDim.x * blockDim.x;
  for (; i < n4; i += stride){
    f32x4 v = ((const f32x4*)in)[i];
    u16x4 h;
#pragma unroll
    for (int j = 0; j < 4; ++j) h[j] = f2bf(v[j]);
    ((u16x4*)out)[i] = h;
  }
}

// ---------------- shared 128x128 bf16 MFMA main loop (m97 structure) ----------------
__device__ __forceinline__ void gemm_tile_128(
    const u16* A, const u16* B, int K, int bm, int bn,
    u16* lds_a, u16* lds_b, f32x4 acc[4][4])
{
  const int t = threadIdx.x;
  const int lane = t & 63;
  const int wm = (t >> 6) >> 1, wn = (t >> 6) & 1;
  const int g = lane >> 4, r16 = lane & 15;
  const u16* Ab = A + (size_t)bm * 128 * K;
  const u16* Bb = B + (size_t)bn * 128 * K;
  for (int kt = 0; kt < K; kt += 32){
#pragma unroll
    for (int half = 0; half < 2; ++half){
      const int tt = half*256 + t;
      const int row = tt >> 2, col = (tt & 3) * 8;
      gload_lds16(Ab + (size_t)row*K + kt + col, lds_a + tt*8);
      gload_lds16(Bb + (size_t)row*K + kt + col, lds_b + tt*8);
    }
    __syncthreads();
    bf16x8 af[4], bfr[4];
#pragma unroll
    for (int i = 0; i < 4; ++i){
      af[i]  = *(const bf16x8*)(lds_a + (wm*64 + i*16 + r16)*32 + g*8);
      bfr[i] = *(const bf16x8*)(lds_b + (wn*64 + i*16 + r16)*32 + g*8);
    }
#pragma unroll
    for (int a = 0; a < 4; ++a)
#pragma unroll
      for (int b = 0; b < 4; ++b)
        acc[a][b] = mfma16(af[a], bfr[b], acc[a][b]);
    __syncthreads();
  }
}

// ---------------- K3: QKV projection GEMM, scatter epilogue ----------------
__global__ __launch_bounds__(256) void k_gemm_qkv(
    const u16* __restrict__ A, const u16* __restrict__ B, const float* __restrict__ bias,
    u16* __restrict__ qws, u16* __restrict__ kws, u16* __restrict__ vtws)
{
  __shared__ __align__(16) u16 lds_a[128*32];
  __shared__ __align__(16) u16 lds_b[128*32];
  const int bm = blockIdx.x, bn = blockIdx.y;
  f32x4 acc[4][4] = {};
  gemm_tile_128(A, B, DD, bm, bn, lds_a, lds_b, acc);
  const int t = threadIdx.x, lane = t & 63;
  const int wm = (t >> 6) >> 1, wn = (t >> 6) & 1;
  const int g = lane >> 4, r16 = lane & 15;
  const int which = bn >> 4, h = bn & 15;
  const float qscale = 0.08838834764831845f; // 1/sqrt(128)
#pragma unroll
  for (int a = 0; a < 4; ++a){
#pragma unroll
    for (int b = 0; b < 4; ++b){
      const int hd = wn*64 + b*16 + r16;
      const float bi = bias[bn*128 + hd];
      const int s0 = bm*128 + wm*64 + a*16 + g*4;
      if (which == 0){
#pragma unroll
        for (int rr = 0; rr < 4; ++rr)
          qws[((size_t)h*SS + (s0+rr))*HDIM + hd] = f2bf((acc[a][b][rr] + bi) * qscale);
      } else if (which == 1){
#pragma unroll
        for (int rr = 0; rr < 4; ++rr)
          kws[((size_t)h*SS + (s0+rr))*HDIM + hd] = f2bf(acc[a][b][rr] + bi);
      } else {
        u16x4 pk;
#pragma unroll
        for (int rr = 0; rr < 4; ++rr) pk[rr] = f2bf(acc[a][b][rr] + bi);
        *(u16x4*)&vtws[((size_t)h*HDIM + hd)*SS + s0] = pk; // V^T: [H][hd][S]
      }
    }
  }
}

// ---------------- K4: flash attention, swapped-QK^T 32x32, KV-split x4 ----------------
// block = (qb, h): 32 q-rows, 4 waves each over 512 keys; zero-barrier main loop.
// S-tile = mfma(Kfrag, Qfrag): lane owns q = lane&31; k(reg,hi) = (reg&3)+8*(reg>>2)+4*hi.
__global__ __launch_bounds__(256, 2) void k_attn(
    const u16* __restrict__ q, const u16* __restrict__ kk_, const u16* __restrict__ vt,
    const int* __restrict__ seg, u16* __restrict__ o)
{
  __shared__ __align__(16) float obuf[4][4][32][36]; // [wave][dgrp][q][32 d + pad4]
  __shared__ float mlbuf[4][2][32];
  const int qb = blockIdx.x, h = blockIdx.y;
  const int t = threadIdx.x, lane = t & 63, w = t >> 6;
  const int hi = lane >> 5, l31 = lane & 31;
  const int q0 = qb * 32;

  // Q fragments (pre-scaled by 1/sqrt(128)); A/B-frag: row=lane&31, k=(lane>>5)*8+j
  bf16x8 qf[8];
  {
    const u16* qp = q + ((size_t)h*SS + q0 + l31)*HDIM + hi*8;
#pragma unroll
    for (int c = 0; c < 8; ++c) qf[c] = *(const bf16x8*)(qp + c*16);
  }
  const int seg_q = seg[q0 + l31];

  f32x16 oacc[4];
#pragma unroll
  for (int dg = 0; dg < 4; ++dg)
#pragma unroll
    for (int r = 0; r < 16; ++r) oacc[dg][r] = 0.f;
  float m = -1e30f, l = 0.f;

  const u16* kbase = kk_ + ((size_t)h*SS + l31)*HDIM + hi*8;
  const u16* vbase = vt + ((size_t)h*HDIM + l31)*SS + hi*8;

  for (int it = 0; it < 16; ++it){
    const int kb = (w*16 + it)*32;
    // K fragments for this 32-key tile (global, L2-resident)
    bf16x8 kf[8];
    const u16* kp = kbase + (size_t)kb*HDIM;
#pragma unroll
    for (int c = 0; c < 8; ++c) kf[c] = *(const bf16x8*)(kp + c*16);
    // seg quads: sg[rq][j] = seg[kb + rq*8 + hi*4 + j]
    i32x4 sg[4];
#pragma unroll
    for (int rq = 0; rq < 4; ++rq) sg[rq] = *(const i32x4*)(seg + kb + rq*8 + hi*4);
    // V^T fragments: A-frag rows d = dg*32+l31, k-cols = key
    bf16x8 vf[4][2];
#pragma unroll
    for (int dg = 0; dg < 4; ++dg)
#pragma unroll
      for (int ks = 0; ks < 2; ++ks)
        vf[dg][ks] = *(const bf16x8*)(vbase + (size_t)dg*32*SS + kb + ks*16);

    // QK^T swapped: S[k][q]
    f32x16 s;
#pragma unroll
    for (int r = 0; r < 16; ++r) s[r] = 0.f;
#pragma unroll
    for (int c = 0; c < 8; ++c) s = mfma32(kf[c], qf[c], s);

    // additive 0/1 segment mask + tile max
    float tm = -1e30f;
#pragma unroll
    for (int r = 0; r < 16; ++r){
      const int sk = sg[r>>2][r&3];
      s[r] += (sk == seg_q) ? 1.0f : 0.0f;
      tm = fmaxf(tm, s[r]);
    }
    tm = fmaxf(tm, __shfl_xor(tm, 32));
    // defer-max (T13, THR=8)
    if (!__all(tm <= m + 8.0f)){
      const float mn = fmaxf(m, tm);
      const float sc = __expf(m - mn);
      l *= sc;
#pragma unroll
      for (int dg = 0; dg < 4; ++dg)
#pragma unroll
        for (int r = 0; r < 16; ++r) oacc[dg][r] *= sc;
      m = mn;
    }
    // P = exp(S - m), row-sum
    float p[16]; float ts = 0.f;
#pragma unroll
    for (int r = 0; r < 16; ++r){ p[r] = __expf(s[r] - m); ts += p[r]; }
    ts += __shfl_xor(ts, 32);
    l += ts;
    // pack P -> bf16 word pairs; exchange across hi-halves to build B-frags
    unsigned pk_[8];
#pragma unroll
    for (int i = 0; i < 8; ++i)
      pk_[i] = (unsigned)f2bf(p[2*i]) | ((unsigned)f2bf(p[2*i+1]) << 16);
    const unsigned x0 = __shfl_xor(hi ? pk_[0] : pk_[2], 32);
    const unsigned x1 = __shfl_xor(hi ? pk_[1] : pk_[3], 32);
    const unsigned x2 = __shfl_xor(hi ? pk_[4] : pk_[6], 32);
    const unsigned x3 = __shfl_xor(hi ? pk_[5] : pk_[7], 32);
    u32x4 f0, f1;
    f0[0] = hi ? x0 : pk_[0]; f0[1] = hi ? x1 : pk_[1];
    f0[2] = hi ? pk_[2] : x0; f0[3] = hi ? pk_[3] : x1;
    f1[0] = hi ? x2 : pk_[4]; f1[1] = hi ? x3 : pk_[5];
    f1[2] = hi ? pk_[6] : x2; f1[3] = hi ? pk_[7] : x3;
    const bf16x8 pf0 = __builtin_bit_cast(bf16x8, f0);
    const bf16x8 pf1 = __builtin_bit_cast(bf16x8, f1);
    // PV: O^T[d][q] += V^T · P
#pragma unroll
    for (int dg = 0; dg < 4; ++dg){
      oacc[dg] = mfma32(vf[dg][0], pf0, oacc[dg]);
      oacc[dg] = mfma32(vf[dg][1], pf1, oacc[dg]);
    }
  }

  // write partials to LDS: rows (0..3)+8*rq+4*hi per quad
#pragma unroll
  for (int dg = 0; dg < 4; ++dg)
#pragma unroll
    for (int rq = 0; rq < 4; ++rq){
      f32x4 v4;
#pragma unroll
      for (int j = 0; j < 4; ++j) v4[j] = oacc[dg][rq*4 + j];
      *(f32x4*)&obuf[w][dg][l31][rq*8 + hi*4] = v4;
    }
  if (lane < 32){ mlbuf[w][0][l31] = m; mlbuf[w][1][l31] = l; }
  __syncthreads();

  // merge: wave w owns d-group dg=w for all 32 q
  {
    const int dg = w;
    float mw[4], lw[4];
#pragma unroll
    for (int wv = 0; wv < 4; ++wv){ mw[wv] = mlbuf[wv][0][l31]; lw[wv] = mlbuf[wv][1][l31]; }
    const float mstar = fmaxf(fmaxf(mw[0],mw[1]), fmaxf(mw[2],mw[3]));
    float cw[4]; float lstar = 0.f;
#pragma unroll
    for (int wv = 0; wv < 4; ++wv){ cw[wv] = __expf(mw[wv]-mstar); lstar += cw[wv]*lw[wv]; }
    const float inv = 1.0f / lstar;
#pragma unroll
    for (int rq = 0; rq < 4; ++rq){
      f32x4 a4 = {0.f,0.f,0.f,0.f};
#pragma unroll
      for (int wv = 0; wv < 4; ++wv){
        const f32x4 v4 = *(const f32x4*)&obuf[wv][dg][l31][rq*8 + hi*4];
#pragma unroll
        for (int j = 0; j < 4; ++j) a4[j] += v4[j] * cw[wv];
      }
      u16x4 h4;
#pragma unroll
      for (int j = 0; j < 4; ++j) h4[j] = f2bf(a4[j] * inv);
      const int d0 = dg*32 + rq*8 + hi*4;
      *(u16x4*)&o[((size_t)(q0 + l31))*DD + h*HDIM + d0] = h4;
    }
  }
}

// ---------------- K5: output projection GEMM + bias + residual ----------------
__global__ __launch_bounds__(256) void k_gemm_out(
    const u16* __restrict__ A, const u16* __restrict__ B, const float* __restrict__ bias,
    const float* __restrict__ xn32, float* __restrict__ out)
{
  __shared__ __align__(16) u16 lds_a[128*32];
  __shared__ __align__(16) u16 lds_b[128*32];
  const int bm = blockIdx.x, bn = blockIdx.y;
  f32x4 acc[4][4] = {};
  gemm_tile_128(A, B, DD, bm, bn, lds_a, lds_b, acc);
  const int t = threadIdx.x, lane = t & 63;
  const int wm = (t >> 6) >> 1, wn = (t >> 6) & 1;
  const int g = lane >> 4, r16 = lane & 15;
#pragma unroll
  for (int a = 0; a < 4; ++a){
#pragma unroll
    for (int b = 0; b < 4; ++b){
      const int n = bn*128 + wn*64 + b*16 + r16;
      const float bi = bias[n];
#pragma unroll
      for (int rr = 0; rr < 4; ++rr){
        const int s = bm*128 + wm*64 + a*16 + g*4 + rr;
        out[(size_t)s*DD + n] = acc[a][b][rr] + bi + xn32[(size_t)s*DD + n];
      }
    }
  }
}

extern "C" void kernel_launch(void* const* d_in, const int* in_sizes, int n_in,
                              void* d_out, int out_size, void* d_ws, size_t ws_size,
                              hipStream_t stream)
{
  (void)in_sizes; (void)n_in; (void)out_size; (void)ws_size;
  const float* br     = (const float*)d_in[0];
  const int*   cat    = (const int*)d_in[1];
  const int*   cse    = (const int*)d_in[2];
  const int*   cmb    = (const int*)d_in[3];
  const int*   seg    = (const int*)d_in[4];
  const float* cat_e  = (const float*)d_in[5];
  const float* case_e = (const float*)d_in[6];
  const float* comb_e = (const float*)d_in[7];
  const float* ln_g   = (const float*)d_in[8];
  const float* ln_b   = (const float*)d_in[9];
  const float* in_w   = (const float*)d_in[10];
  const float* in_b   = (const float*)d_in[11];
  const float* out_w  = (const float*)d_in[12];
  const float* out_b  = (const float*)d_in[13];
  float* out = (float*)d_out;

  char* ws = (char*)d_ws;
  float* xn32  = (float*)(ws);                     // 16 MiB
  u16*   xn16  = (u16*)(ws + 16777216);            // 8 MiB
  u16*   inw16 = (u16*)(ws + 25165824);            // 24 MiB
  u16*   outw16= (u16*)(ws + 50331648);            // 8 MiB
  u16*   qws   = (u16*)(ws + 58720256);            // 8 MiB  [H][S][hd], pre-scaled
  u16*   kws   = (u16*)(ws + 67108864);            // 8 MiB  [H][S][hd]
  u16*   vtws  = (u16*)(ws + 75497472);            // 8 MiB  [H][hd][S]
  u16*   ows   = (u16*)(ws + 83886080);            // 8 MiB  [S][D]

  k_embed_ln<<<SS, 256, 0, stream>>>(br, cat, cse, cmb, cat_e, case_e, comb_e,
                                     ln_g, ln_b, xn32, xn16);
  k_f32_to_bf16<<<2048, 256, 0, stream>>>(in_w, inw16, 3*DD*DD/4);
  k_f32_to_bf16<<<2048, 256, 0, stream>>>(out_w, outw16, DD*DD/4);
  dim3 g1(16, 48);
  k_gemm_qkv<<<g1, 256, 0, stream>>>(xn16, inw16, in_b, qws, kws, vtws);
  dim3 g2(64, 16);
  k_attn<<<g2, 256, 0, stream>>>(qws, kws, vtws, seg, ows);
  dim3 g3(16, 16);
  k_gemm_out<<<g3, 256, 0, stream>>>(ows, outw16, out_b, xn32, out);
}

// Round 3
// 381.255 us; speedup vs baseline: 1.0494x; 1.0494x over previous
//
#include <hip/hip_runtime.h>
#include <hip/hip_bf16.h>

#define SS 2048
#define DD 2048
#define HH 16
#define HDIM 128

typedef unsigned short u16;
typedef __attribute__((ext_vector_type(8))) short bf16x8;
typedef __attribute__((ext_vector_type(4))) float f32x4;
typedef __attribute__((ext_vector_type(16))) float f32x16;
typedef __attribute__((ext_vector_type(4))) unsigned short u16x4;
typedef __attribute__((ext_vector_type(4))) int i32x4;
typedef __attribute__((ext_vector_type(4))) unsigned int u32x4;

__device__ __forceinline__ u16 f2bf(float f){
  unsigned u = __float_as_uint(f);
  u += 0x7FFFu + ((u >> 16) & 1u);
  return (u16)(u >> 16);
}

__device__ __forceinline__ void gload_lds16(const void* g, void* l){
  __builtin_amdgcn_global_load_lds(
      (const __attribute__((address_space(1))) void*)g,
      (__attribute__((address_space(3))) void*)l, 16, 0, 0);
}

__device__ __forceinline__ f32x4 mfma16(bf16x8 a, bf16x8 b, f32x4 c){
  return __builtin_amdgcn_mfma_f32_16x16x32_bf16(a, b, c, 0, 0, 0);
}
__device__ __forceinline__ f32x16 mfma32(bf16x8 a, bf16x8 b, f32x16 c){
  return __builtin_amdgcn_mfma_f32_32x32x16_bf16(a, b, c, 0, 0, 0);
}

// ---------------- K1: fused embedding add + LayerNorm ----------------
__global__ __launch_bounds__(256) void k_embed_ln(
    const float* __restrict__ br, const int* __restrict__ cat,
    const int* __restrict__ cse, const int* __restrict__ cmb,
    const float* __restrict__ cat_e, const float* __restrict__ case_e,
    const float* __restrict__ comb_e, const float* __restrict__ lg,
    const float* __restrict__ lb, float* __restrict__ xn32, u16* __restrict__ xn16)
{
  const int s = blockIdx.x, t = threadIdx.x;
  const int lane = t & 63, wave = t >> 6;
  const int c0 = cat[s], c1 = cse[s], c2 = cmb[s];
  const f32x4* pb = (const f32x4*)(br + (size_t)s * DD);
  const f32x4* e0 = (const f32x4*)(cat_e + (size_t)c0 * DD);
  const f32x4* e1 = (const f32x4*)(case_e + (size_t)c1 * DD);
  const f32x4* e2 = (const f32x4*)(comb_e + (size_t)c2 * DD);
  f32x4 xa = pb[t] + e0[t] + e1[t] + e2[t];
  f32x4 xb = pb[t+256] + e0[t+256] + e1[t+256] + e2[t+256];
  float s1 = 0.f, s2 = 0.f;
#pragma unroll
  for (int i = 0; i < 4; ++i){ s1 += xa[i] + xb[i]; s2 += xa[i]*xa[i] + xb[i]*xb[i]; }
#pragma unroll
  for (int off = 32; off > 0; off >>= 1){ s1 += __shfl_down(s1, off); s2 += __shfl_down(s2, off); }
  __shared__ float red[8];
  if (lane == 0){ red[wave*2] = s1; red[wave*2+1] = s2; }
  __syncthreads();
  const float t1 = red[0]+red[2]+red[4]+red[6];
  const float t2 = red[1]+red[3]+red[5]+red[7];
  const float mean = t1 * (1.0f/DD);
  const float var  = t2 * (1.0f/DD) - mean*mean;
  const float rstd = rsqrtf(var + 1e-5f);
  const f32x4* g4 = (const f32x4*)lg;
  const f32x4* b4 = (const f32x4*)lb;
  f32x4 ga = g4[t], gb = g4[t+256], ba = b4[t], bb = b4[t+256];
  f32x4 ya, yb; u16x4 ha, hb;
#pragma unroll
  for (int i = 0; i < 4; ++i){
    ya[i] = (xa[i]-mean)*rstd*ga[i] + ba[i];
    yb[i] = (xb[i]-mean)*rstd*gb[i] + bb[i];
    ha[i] = f2bf(ya[i]); hb[i] = f2bf(yb[i]);
  }
  ((f32x4*)(xn32 + (size_t)s*DD))[t]     = ya;
  ((f32x4*)(xn32 + (size_t)s*DD))[t+256] = yb;
  ((u16x4*)(xn16 + (size_t)s*DD))[t]     = ha;
  ((u16x4*)(xn16 + (size_t)s*DD))[t+256] = hb;
}

// ---------------- K2: f32 -> bf16 convert (vectorized, grid-stride) ----------------
__global__ __launch_bounds__(256) void k_f32_to_bf16(
    const float* __restrict__ in, u16* __restrict__ out, int n4)
{
  int i = blockIdx.x * blockDim.x + threadIdx.x;
  const int stride = gridDim.x * blockDim.x;
  for (; i < n4; i += stride){
    f32x4 v = ((const f32x4*)in)[i];
    u16x4 h;
#pragma unroll
    for (int j = 0; j < 4; ++j) h[j] = f2bf(v[j]);
    ((u16x4*)out)[i] = h;
  }
}

// ---------------- shared 128x128 bf16 MFMA main loop (m97 structure) ----------------
__device__ __forceinline__ void gemm_tile_128(
    const u16* A, const u16* B, int K, int bm, int bn,
    u16* lds_a, u16* lds_b, f32x4 acc[4][4])
{
  const int t = threadIdx.x;
  const int lane = t & 63;
  const int wm = (t >> 6) >> 1, wn = (t >> 6) & 1;
  const int g = lane >> 4, r16 = lane & 15;
  const u16* Ab = A + (size_t)bm * 128 * K;
  const u16* Bb = B + (size_t)bn * 128 * K;
  for (int kt = 0; kt < K; kt += 32){
#pragma unroll
    for (int half = 0; half < 2; ++half){
      const int tt = half*256 + t;
      const int row = tt >> 2, col = (tt & 3) * 8;
      gload_lds16(Ab + (size_t)row*K + kt + col, lds_a + tt*8);
      gload_lds16(Bb + (size_t)row*K + kt + col, lds_b + tt*8);
    }
    __syncthreads();
    bf16x8 af[4], bfr[4];
#pragma unroll
    for (int i = 0; i < 4; ++i){
      af[i]  = *(const bf16x8*)(lds_a + (wm*64 + i*16 + r16)*32 + g*8);
      bfr[i] = *(const bf16x8*)(lds_b + (wn*64 + i*16 + r16)*32 + g*8);
    }
#pragma unroll
    for (int a = 0; a < 4; ++a)
#pragma unroll
      for (int b = 0; b < 4; ++b)
        acc[a][b] = mfma16(af[a], bfr[b], acc[a][b]);
    __syncthreads();
  }
}

// ---------------- K3: QKV projection GEMM, scatter epilogue ----------------
__global__ __launch_bounds__(256) void k_gemm_qkv(
    const u16* __restrict__ A, const u16* __restrict__ B, const float* __restrict__ bias,
    u16* __restrict__ qws, u16* __restrict__ kws, u16* __restrict__ vtws)
{
  __shared__ __align__(16) u16 lds_a[128*32];
  __shared__ __align__(16) u16 lds_b[128*32];
  const int bm = blockIdx.x, bn = blockIdx.y;
  f32x4 acc[4][4] = {};
  gemm_tile_128(A, B, DD, bm, bn, lds_a, lds_b, acc);
  const int t = threadIdx.x, lane = t & 63;
  const int wm = (t >> 6) >> 1, wn = (t >> 6) & 1;
  const int g = lane >> 4, r16 = lane & 15;
  const int which = bn >> 4, h = bn & 15;
  const float qscale = 0.08838834764831845f; // 1/sqrt(128)
#pragma unroll
  for (int a = 0; a < 4; ++a){
#pragma unroll
    for (int b = 0; b < 4; ++b){
      const int hd = wn*64 + b*16 + r16;
      const float bi = bias[bn*128 + hd];
      const int s0 = bm*128 + wm*64 + a*16 + g*4;
      if (which == 0){
#pragma unroll
        for (int rr = 0; rr < 4; ++rr)
          qws[((size_t)h*SS + (s0+rr))*HDIM + hd] = f2bf((acc[a][b][rr] + bi) * qscale);
      } else if (which == 1){
#pragma unroll
        for (int rr = 0; rr < 4; ++rr)
          kws[((size_t)h*SS + (s0+rr))*HDIM + hd] = f2bf(acc[a][b][rr] + bi);
      } else {
        u16x4 pk;
#pragma unroll
        for (int rr = 0; rr < 4; ++rr) pk[rr] = f2bf(acc[a][b][rr] + bi);
        *(u16x4*)&vtws[((size_t)h*HDIM + hd)*SS + s0] = pk; // V^T: [H][hd][S]
      }
    }
  }
}

// ---------------- K4: flash attention, swapped-QK^T 32x32 ----------------
// block = 128 q-rows x full K/V sweep; 4 waves each own one 32-row q-tile.
// K/VT tiles (32 keys) LDS-staged via global_load_lds, double-buffered,
// XOR-swizzled (K: slot^=(row&7), VT: slot^=(row&3)); XCD-head swizzle.
__global__ __launch_bounds__(256, 1) void k_attn(
    const u16* __restrict__ q, const u16* __restrict__ kk_, const u16* __restrict__ vt,
    const int* __restrict__ seg, u16* __restrict__ o)
{
  __shared__ __align__(16) u16 kbuf[2][32*128];   // [buf][32 keys][128 d] swizzled
  __shared__ __align__(16) u16 vbuf[2][128*32];   // [buf][128 d][32 keys] swizzled
  const int bid = blockIdx.x;
  const int xcd = bid & 7, ii = bid >> 3;
  const int h = xcd*2 + (ii >> 4), qb = ii & 15;   // 2 heads per XCD -> L2-local K/V
  const int t = threadIdx.x, lane = t & 63, w = t >> 6;
  const int hi = lane >> 5, l31 = lane & 31;
  const int q0 = qb*128 + w*32;

  const char* khead  = (const char*)(kk_ + (size_t)h*SS*HDIM);
  const char* vthead = (const char*)(vt  + (size_t)h*HDIM*SS);

  // Q fragments (pre-scaled by 1/sqrt(128)); A/B-frag: row=lane&31, k=(lane>>5)*8+j
  bf16x8 qf[8];
  {
    const u16* qp = q + ((size_t)h*SS + q0 + l31)*HDIM + hi*8;
#pragma unroll
    for (int c = 0; c < 8; ++c) qf[c] = *(const bf16x8*)(qp + c*16);
  }
  const int seg_q = seg[q0 + l31];

  f32x16 oacc[4];
#pragma unroll
  for (int dg = 0; dg < 4; ++dg)
#pragma unroll
    for (int r = 0; r < 16; ++r) oacc[dg][r] = 0.f;
  float m = -1e30f, l = 0.f;

  // prologue: stage tile 0 into buf 0
#pragma unroll
  for (int i = 0; i < 2; ++i){
    const int ci = i*256 + t;
    { const int row = ci >> 4, slot = ci & 15;
      gload_lds16(khead + (size_t)row*256 + ((slot ^ (row & 7))*16),
                  (char*)kbuf[0] + ci*16); }
    { const int row = ci >> 2, slot = ci & 3;
      gload_lds16(vthead + (size_t)row*(SS*2) + ((slot ^ (row & 3))*16),
                  (char*)vbuf[0] + ci*16); }
  }
  __syncthreads();

  for (int it = 0; it < 64; ++it){
    const int cur = it & 1;
    // stage next tile into the other buffer (overlaps with compute below)
    if (it < 63){
      const int kb2 = (it+1)*32;
#pragma unroll
      for (int i = 0; i < 2; ++i){
        const int ci = i*256 + t;
        { const int row = ci >> 4, slot = ci & 15;
          gload_lds16(khead + (size_t)(kb2 + row)*256 + ((slot ^ (row & 7))*16),
                      (char*)kbuf[cur^1] + ci*16); }
        { const int row = ci >> 2, slot = ci & 3;
          gload_lds16(vthead + (size_t)row*(SS*2) + (size_t)kb2*2 + ((slot ^ (row & 3))*16),
                      (char*)vbuf[cur^1] + ci*16); }
      }
    }
    const int kb = it*32;
    // K fragments from LDS (swizzled read)
    bf16x8 kf[8];
    const char* kl = (const char*)kbuf[cur] + l31*256;
#pragma unroll
    for (int c = 0; c < 8; ++c)
      kf[c] = *(const bf16x8*)(kl + (((hi + 2*c) ^ (l31 & 7))*16));
    // seg quads: sg[rq][j] = seg[kb + rq*8 + hi*4 + j]
    i32x4 sg[4];
#pragma unroll
    for (int rq = 0; rq < 4; ++rq) sg[rq] = *(const i32x4*)(seg + kb + rq*8 + hi*4);
    // V^T fragments from LDS: rows d = dg*32+l31
    bf16x8 vf[4][2];
#pragma unroll
    for (int dg = 0; dg < 4; ++dg)
#pragma unroll
      for (int ks = 0; ks < 2; ++ks)
        vf[dg][ks] = *(const bf16x8*)((const char*)vbuf[cur]
                        + (dg*32 + l31)*64 + (((hi + 2*ks) ^ (l31 & 3))*16));

    // QK^T swapped: S[k][q]
    f32x16 s;
#pragma unroll
    for (int r = 0; r < 16; ++r) s[r] = 0.f;
#pragma unroll
    for (int c = 0; c < 8; ++c) s = mfma32(kf[c], qf[c], s);

    // additive 0/1 segment mask + tile max
    float tm = -1e30f;
#pragma unroll
    for (int r = 0; r < 16; ++r){
      const int sk = sg[r>>2][r&3];
      s[r] += (sk == seg_q) ? 1.0f : 0.0f;
      tm = fmaxf(tm, s[r]);
    }
    tm = fmaxf(tm, __shfl_xor(tm, 32));
    // defer-max (T13, THR=8)
    if (!__all(tm <= m + 8.0f)){
      const float mn = fmaxf(m, tm);
      const float sc = __expf(m - mn);
      l *= sc;
#pragma unroll
      for (int dg = 0; dg < 4; ++dg)
#pragma unroll
        for (int r = 0; r < 16; ++r) oacc[dg][r] *= sc;
      m = mn;
    }
    // P = exp(S - m), row-sum
    float p[16]; float ts = 0.f;
#pragma unroll
    for (int r = 0; r < 16; ++r){ p[r] = __expf(s[r] - m); ts += p[r]; }
    ts += __shfl_xor(ts, 32);
    l += ts;
    // pack P -> bf16 word pairs; exchange across hi-halves to build B-frags
    unsigned pk_[8];
#pragma unroll
    for (int i = 0; i < 8; ++i)
      pk_[i] = (unsigned)f2bf(p[2*i]) | ((unsigned)f2bf(p[2*i+1]) << 16);
    const unsigned x0 = __shfl_xor(hi ? pk_[0] : pk_[2], 32);
    const unsigned x1 = __shfl_xor(hi ? pk_[1] : pk_[3], 32);
    const unsigned x2 = __shfl_xor(hi ? pk_[4] : pk_[6], 32);
    const unsigned x3 = __shfl_xor(hi ? pk_[5] : pk_[7], 32);
    u32x4 f0, f1;
    f0[0] = hi ? x0 : pk_[0]; f0[1] = hi ? x1 : pk_[1];
    f0[2] = hi ? pk_[2] : x0; f0[3] = hi ? pk_[3] : x1;
    f1[0] = hi ? x2 : pk_[4]; f1[1] = hi ? x3 : pk_[5];
    f1[2] = hi ? pk_[6] : x2; f1[3] = hi ? pk_[7] : x3;
    const bf16x8 pf0 = __builtin_bit_cast(bf16x8, f0);
    const bf16x8 pf1 = __builtin_bit_cast(bf16x8, f1);
    // PV: O^T[d][q] += V^T . P
#pragma unroll
    for (int dg = 0; dg < 4; ++dg){
      oacc[dg] = mfma32(vf[dg][0], pf0, oacc[dg]);
      oacc[dg] = mfma32(vf[dg][1], pf1, oacc[dg]);
    }
    __syncthreads();  // next tile staged AND this tile's LDS reads done
  }

  // epilogue: divide by denom, write o bf16 [S][D]
  const float inv = 1.0f / l;
#pragma unroll
  for (int dg = 0; dg < 4; ++dg)
#pragma unroll
    for (int rq = 0; rq < 4; ++rq){
      u16x4 h4;
#pragma unroll
      for (int j = 0; j < 4; ++j) h4[j] = f2bf(oacc[dg][rq*4 + j] * inv);
      const int d0 = dg*32 + rq*8 + hi*4;
      *(u16x4*)&o[((size_t)(q0 + l31))*DD + h*HDIM + d0] = h4;
    }
}

// ---------------- K5: output projection GEMM + bias + residual ----------------
__global__ __launch_bounds__(256) void k_gemm_out(
    const u16* __restrict__ A, const u16* __restrict__ B, const float* __restrict__ bias,
    const float* __restrict__ xn32, float* __restrict__ out)
{
  __shared__ __align__(16) u16 lds_a[128*32];
  __shared__ __align__(16) u16 lds_b[128*32];
  const int bm = blockIdx.x, bn = blockIdx.y;
  f32x4 acc[4][4] = {};
  gemm_tile_128(A, B, DD, bm, bn, lds_a, lds_b, acc);
  const int t = threadIdx.x, lane = t & 63;
  const int wm = (t >> 6) >> 1, wn = (t >> 6) & 1;
  const int g = lane >> 4, r16 = lane & 15;
#pragma unroll
  for (int a = 0; a < 4; ++a){
#pragma unroll
    for (int b = 0; b < 4; ++b){
      const int n = bn*128 + wn*64 + b*16 + r16;
      const float bi = bias[n];
#pragma unroll
      for (int rr = 0; rr < 4; ++rr){
        const int s = bm*128 + wm*64 + a*16 + g*4 + rr;
        out[(size_t)s*DD + n] = acc[a][b][rr] + bi + xn32[(size_t)s*DD + n];
      }
    }
  }
}

extern "C" void kernel_launch(void* const* d_in, const int* in_sizes, int n_in,
                              void* d_out, int out_size, void* d_ws, size_t ws_size,
                              hipStream_t stream)
{
  (void)in_sizes; (void)n_in; (void)out_size; (void)ws_size;
  const float* br     = (const float*)d_in[0];
  const int*   cat    = (const int*)d_in[1];
  const int*   cse    = (const int*)d_in[2];
  const int*   cmb    = (const int*)d_in[3];
  const int*   seg    = (const int*)d_in[4];
  const float* cat_e  = (const float*)d_in[5];
  const float* case_e = (const float*)d_in[6];
  const float* comb_e = (const float*)d_in[7];
  const float* ln_g   = (const float*)d_in[8];
  const float* ln_b   = (const float*)d_in[9];
  const float* in_w   = (const float*)d_in[10];
  const float* in_b   = (const float*)d_in[11];
  const float* out_w  = (const float*)d_in[12];
  const float* out_b  = (const float*)d_in[13];
  float* out = (float*)d_out;

  char* ws = (char*)d_ws;
  float* xn32  = (float*)(ws);                     // 16 MiB
  u16*   xn16  = (u16*)(ws + 16777216);            // 8 MiB
  u16*   inw16 = (u16*)(ws + 25165824);            // 24 MiB
  u16*   outw16= (u16*)(ws + 50331648);            // 8 MiB
  u16*   qws   = (u16*)(ws + 58720256);            // 8 MiB  [H][S][hd], pre-scaled
  u16*   kws   = (u16*)(ws + 67108864);            // 8 MiB  [H][S][hd]
  u16*   vtws  = (u16*)(ws + 75497472);            // 8 MiB  [H][hd][S]
  u16*   ows   = (u16*)(ws + 83886080);            // 8 MiB  [S][D]

  k_embed_ln<<<SS, 256, 0, stream>>>(br, cat, cse, cmb, cat_e, case_e, comb_e,
                                     ln_g, ln_b, xn32, xn16);
  k_f32_to_bf16<<<2048, 256, 0, stream>>>(in_w, inw16, 3*DD*DD/4);
  k_f32_to_bf16<<<2048, 256, 0, stream>>>(out_w, outw16, DD*DD/4);
  dim3 g1(16, 48);
  k_gemm_qkv<<<g1, 256, 0, stream>>>(xn16, inw16, in_b, qws, kws, vtws);
  k_attn<<<256, 256, 0, stream>>>(qws, kws, vtws, seg, ows);
  dim3 g3(16, 16);
  k_gemm_out<<<g3, 256, 0, stream>>>(ows, outw16, out_b, xn32, out);
}

// Round 4
// 339.147 us; speedup vs baseline: 1.1797x; 1.1242x over previous
//
#include <hip/hip_runtime.h>
#include <hip/hip_bf16.h>

#define SS 2048
#define DD 2048
#define HH 16
#define HDIM 128

typedef unsigned short u16;
typedef __attribute__((ext_vector_type(8))) short bf16x8;
typedef __attribute__((ext_vector_type(4))) float f32x4;
typedef __attribute__((ext_vector_type(16))) float f32x16;
typedef __attribute__((ext_vector_type(4))) unsigned short u16x4;
typedef __attribute__((ext_vector_type(4))) int i32x4;
typedef __attribute__((ext_vector_type(4))) unsigned int u32x4;

__device__ __forceinline__ u16 f2bf(float f){
  unsigned u = __float_as_uint(f);
  u += 0x7FFFu + ((u >> 16) & 1u);
  return (u16)(u >> 16);
}

__device__ __forceinline__ void gload_lds16(const void* g, void* l){
  __builtin_amdgcn_global_load_lds(
      (const __attribute__((address_space(1))) void*)g,
      (__attribute__((address_space(3))) void*)l, 16, 0, 0);
}

__device__ __forceinline__ f32x4 mfma16(bf16x8 a, bf16x8 b, f32x4 c){
  return __builtin_amdgcn_mfma_f32_16x16x32_bf16(a, b, c, 0, 0, 0);
}
__device__ __forceinline__ f32x16 mfma32(bf16x8 a, bf16x8 b, f32x16 c){
  return __builtin_amdgcn_mfma_f32_32x32x16_bf16(a, b, c, 0, 0, 0);
}

// ---------------- K1: fused embedding add + LayerNorm ----------------
__global__ __launch_bounds__(256) void k_embed_ln(
    const float* __restrict__ br, const int* __restrict__ cat,
    const int* __restrict__ cse, const int* __restrict__ cmb,
    const float* __restrict__ cat_e, const float* __restrict__ case_e,
    const float* __restrict__ comb_e, const float* __restrict__ lg,
    const float* __restrict__ lb, float* __restrict__ xn32, u16* __restrict__ xn16)
{
  const int s = blockIdx.x, t = threadIdx.x;
  const int lane = t & 63, wave = t >> 6;
  const int c0 = cat[s], c1 = cse[s], c2 = cmb[s];
  const f32x4* pb = (const f32x4*)(br + (size_t)s * DD);
  const f32x4* e0 = (const f32x4*)(cat_e + (size_t)c0 * DD);
  const f32x4* e1 = (const f32x4*)(case_e + (size_t)c1 * DD);
  const f32x4* e2 = (const f32x4*)(comb_e + (size_t)c2 * DD);
  f32x4 xa = pb[t] + e0[t] + e1[t] + e2[t];
  f32x4 xb = pb[t+256] + e0[t+256] + e1[t+256] + e2[t+256];
  float s1 = 0.f, s2 = 0.f;
#pragma unroll
  for (int i = 0; i < 4; ++i){ s1 += xa[i] + xb[i]; s2 += xa[i]*xa[i] + xb[i]*xb[i]; }
#pragma unroll
  for (int off = 32; off > 0; off >>= 1){ s1 += __shfl_down(s1, off); s2 += __shfl_down(s2, off); }
  __shared__ float red[8];
  if (lane == 0){ red[wave*2] = s1; red[wave*2+1] = s2; }
  __syncthreads();
  const float t1 = red[0]+red[2]+red[4]+red[6];
  const float t2 = red[1]+red[3]+red[5]+red[7];
  const float mean = t1 * (1.0f/DD);
  const float var  = t2 * (1.0f/DD) - mean*mean;
  const float rstd = rsqrtf(var + 1e-5f);
  const f32x4* g4 = (const f32x4*)lg;
  const f32x4* b4 = (const f32x4*)lb;
  f32x4 ga = g4[t], gb = g4[t+256], ba = b4[t], bb = b4[t+256];
  f32x4 ya, yb; u16x4 ha, hb;
#pragma unroll
  for (int i = 0; i < 4; ++i){
    ya[i] = (xa[i]-mean)*rstd*ga[i] + ba[i];
    yb[i] = (xb[i]-mean)*rstd*gb[i] + bb[i];
    ha[i] = f2bf(ya[i]); hb[i] = f2bf(yb[i]);
  }
  ((f32x4*)(xn32 + (size_t)s*DD))[t]     = ya;
  ((f32x4*)(xn32 + (size_t)s*DD))[t+256] = yb;
  ((u16x4*)(xn16 + (size_t)s*DD))[t]     = ha;
  ((u16x4*)(xn16 + (size_t)s*DD))[t+256] = hb;
}

// ---------------- K2: f32 -> bf16 convert (vectorized, grid-stride) ----------------
__global__ __launch_bounds__(256) void k_f32_to_bf16(
    const float* __restrict__ in, u16* __restrict__ out, int n4)
{
  int i = blockIdx.x * blockDim.x + threadIdx.x;
  const int stride = gridDim.x * blockDim.x;
  for (; i < n4; i += stride){
    f32x4 v = ((const f32x4*)in)[i];
    u16x4 h;
#pragma unroll
    for (int j = 0; j < 4; ++j) h[j] = f2bf(v[j]);
    ((u16x4*)out)[i] = h;
  }
}

// ---------------- shared 128x128 bf16 MFMA main loop (m97 structure) ----------------
__device__ __forceinline__ void gemm_tile_128(
    const u16* A, const u16* B, int K, int bm, int bn,
    u16* lds_a, u16* lds_b, f32x4 acc[4][4])
{
  const int t = threadIdx.x;
  const int lane = t & 63;
  const int wm = (t >> 6) >> 1, wn = (t >> 6) & 1;
  const int g = lane >> 4, r16 = lane & 15;
  const u16* Ab = A + (size_t)bm * 128 * K;
  const u16* Bb = B + (size_t)bn * 128 * K;
  for (int kt = 0; kt < K; kt += 32){
#pragma unroll
    for (int half = 0; half < 2; ++half){
      const int tt = half*256 + t;
      const int row = tt >> 2, col = (tt & 3) * 8;
      gload_lds16(Ab + (size_t)row*K + kt + col, lds_a + tt*8);
      gload_lds16(Bb + (size_t)row*K + kt + col, lds_b + tt*8);
    }
    __syncthreads();
    bf16x8 af[4], bfr[4];
#pragma unroll
    for (int i = 0; i < 4; ++i){
      af[i]  = *(const bf16x8*)(lds_a + (wm*64 + i*16 + r16)*32 + g*8);
      bfr[i] = *(const bf16x8*)(lds_b + (wn*64 + i*16 + r16)*32 + g*8);
    }
#pragma unroll
    for (int a = 0; a < 4; ++a)
#pragma unroll
      for (int b = 0; b < 4; ++b)
        acc[a][b] = mfma16(af[a], bfr[b], acc[a][b]);
    __syncthreads();
  }
}

// ---------------- K3: QKV projection GEMM, scatter epilogue ----------------
__global__ __launch_bounds__(256) void k_gemm_qkv(
    const u16* __restrict__ A, const u16* __restrict__ B, const float* __restrict__ bias,
    u16* __restrict__ qws, u16* __restrict__ kws, u16* __restrict__ vtws)
{
  __shared__ __align__(16) u16 lds_a[128*32];
  __shared__ __align__(16) u16 lds_b[128*32];
  // bijective XCD swizzle: 768 blocks, each XCD gets 96 consecutive wg
  const int wg = (blockIdx.x & 7)*96 + (blockIdx.x >> 3);
  const int bm = wg & 15, bn = wg >> 4;
  f32x4 acc[4][4] = {};
  gemm_tile_128(A, B, DD, bm, bn, lds_a, lds_b, acc);
  const int t = threadIdx.x, lane = t & 63;
  const int wm = (t >> 6) >> 1, wn = (t >> 6) & 1;
  const int g = lane >> 4, r16 = lane & 15;
  const int which = bn >> 4, h = bn & 15;
  const float qscale = 0.08838834764831845f; // 1/sqrt(128)
#pragma unroll
  for (int a = 0; a < 4; ++a){
#pragma unroll
    for (int b = 0; b < 4; ++b){
      const int hd = wn*64 + b*16 + r16;
      const float bi = bias[bn*128 + hd];
      const int s0 = bm*128 + wm*64 + a*16 + g*4;
      if (which == 0){
#pragma unroll
        for (int rr = 0; rr < 4; ++rr)
          qws[((size_t)h*SS + (s0+rr))*HDIM + hd] = f2bf((acc[a][b][rr] + bi) * qscale);
      } else if (which == 1){
#pragma unroll
        for (int rr = 0; rr < 4; ++rr)
          kws[((size_t)h*SS + (s0+rr))*HDIM + hd] = f2bf(acc[a][b][rr] + bi);
      } else {
        u16x4 pk;
#pragma unroll
        for (int rr = 0; rr < 4; ++rr) pk[rr] = f2bf(acc[a][b][rr] + bi);
        *(u16x4*)&vtws[((size_t)h*HDIM + hd)*SS + s0] = pk; // V^T: [H][hd][S]
      }
    }
  }
}

// ---------------- K4: flash attention, swapped-QK^T 32x32, 2 blocks/CU ----------------
// block = 64 q-rows, 4 waves: wave w -> q-tile (w&1), key-parity (w>>1).
// Per iter stage 64 keys (K 16KB + VT 16KB), double-buffered; 2-way merge at end.
__global__ __launch_bounds__(256, 2) void k_attn(
    const u16* __restrict__ q, const u16* __restrict__ kk_, const u16* __restrict__ vt,
    const int* __restrict__ seg, u16* __restrict__ o)
{
  __shared__ __align__(16) char smem[65536];   // kbuf[2]:0..32K, vbuf[2]:32..64K; merge overlay
  __shared__ float stats[2][2][32];
  const int bid = blockIdx.x;
  const int xcd = bid & 7, ii = bid >> 3;
  const int h = xcd*2 + (ii >> 5), qb = ii & 31;   // 2 heads per XCD
  const int t = threadIdx.x, lane = t & 63, w = t >> 6;
  const int hi = lane >> 5, l31 = lane & 31;
  const int p = w >> 1, qt = w & 1;
  const int q0 = qb*64 + qt*32;

  const char* khead  = (const char*)(kk_ + (size_t)h*SS*HDIM);
  const char* vthead = (const char*)(vt  + (size_t)h*HDIM*SS);

  // Q fragments (pre-scaled); A/B-frag: row=lane&31, k=(lane>>5)*8+j
  bf16x8 qf[8];
  {
    const u16* qp = q + ((size_t)h*SS + q0 + l31)*HDIM + hi*8;
#pragma unroll
    for (int c = 0; c < 8; ++c) qf[c] = *(const bf16x8*)(qp + c*16);
  }
  const int seg_q = seg[q0 + l31];
  const int swz = l31 & 7;

  f32x16 oacc[4];
#pragma unroll
  for (int dg = 0; dg < 4; ++dg)
#pragma unroll
    for (int r = 0; r < 16; ++r) oacc[dg][r] = 0.f;
  float m = -1e30f, l = 0.f;

  // stage 64-key tile kb into buffer buf (K: [64 rows][16 slots], VT: [128 rows][8 slots])
  auto stage = [&](int buf, int kb){
#pragma unroll
    for (int i = 0; i < 4; ++i){
      const int ci = i*256 + t;
      const int row = ci >> 4, slot = ci & 15;
      gload_lds16(khead + (size_t)(kb + row)*256 + ((slot ^ (row & 7))*16),
                  smem + buf*16384 + ci*16);
    }
#pragma unroll
    for (int i = 0; i < 4; ++i){
      const int ci = i*256 + t;
      const int row = ci >> 3, slot = ci & 7;
      gload_lds16(vthead + (size_t)row*(SS*2) + (size_t)kb*2 + ((slot ^ (row & 7))*16),
                  smem + 32768 + buf*16384 + ci*16);
    }
  };

  stage(0, 0);
  __syncthreads();

  for (int it = 0; it < 32; ++it){
    const int cur = it & 1;
    if (it < 31) stage(cur^1, (it+1)*64);

    // K fragments from LDS (swizzled read); wave's keys = it*64 + p*32 ..+31
    bf16x8 kf[8];
    const char* kl = smem + cur*16384 + (p*32 + l31)*256;
#pragma unroll
    for (int c = 0; c < 8; ++c)
      kf[c] = *(const bf16x8*)(kl + (((2*c + hi) ^ swz)*16));
    const int kb_w = it*64 + p*32;
    i32x4 sg[4];
#pragma unroll
    for (int rq = 0; rq < 4; ++rq) sg[rq] = *(const i32x4*)(seg + kb_w + rq*8 + hi*4);
    bf16x8 vf[4][2];
#pragma unroll
    for (int dg = 0; dg < 4; ++dg){
      const char* vl = smem + 32768 + cur*16384 + (dg*32 + l31)*128;
#pragma unroll
      for (int ks = 0; ks < 2; ++ks)
        vf[dg][ks] = *(const bf16x8*)(vl + (((p*4 + 2*ks + hi) ^ swz)*16));
    }

    // QK^T swapped, two 4-deep chains
    f32x16 se, so;
#pragma unroll
    for (int r = 0; r < 16; ++r){ se[r] = 0.f; so[r] = 0.f; }
#pragma unroll
    for (int c = 0; c < 4; ++c){
      se = mfma32(kf[2*c],   qf[2*c],   se);
      so = mfma32(kf[2*c+1], qf[2*c+1], so);
    }
    f32x16 s = se + so;

    // additive 0/1 segment mask + tile max
    float tm = -1e30f;
#pragma unroll
    for (int r = 0; r < 16; ++r){
      const int sk = sg[r>>2][r&3];
      s[r] += (sk == seg_q) ? 1.0f : 0.0f;
      tm = fmaxf(tm, s[r]);
    }
    tm = fmaxf(tm, __shfl_xor(tm, 32));
    // defer-max (T13, THR=8)
    if (!__all(tm <= m + 8.0f)){
      const float mn = fmaxf(m, tm);
      const float sc = __expf(m - mn);
      l *= sc;
#pragma unroll
      for (int dg = 0; dg < 4; ++dg)
#pragma unroll
        for (int r = 0; r < 16; ++r) oacc[dg][r] *= sc;
      m = mn;
    }
    float pr[16]; float ts = 0.f;
#pragma unroll
    for (int r = 0; r < 16; ++r){ pr[r] = __expf(s[r] - m); ts += pr[r]; }
    ts += __shfl_xor(ts, 32);
    l += ts;
    // pack P -> bf16; exchange across hi-halves to build B-frags
    unsigned pk_[8];
#pragma unroll
    for (int i = 0; i < 8; ++i)
      pk_[i] = (unsigned)f2bf(pr[2*i]) | ((unsigned)f2bf(pr[2*i+1]) << 16);
    const unsigned x0 = __shfl_xor(hi ? pk_[0] : pk_[2], 32);
    const unsigned x1 = __shfl_xor(hi ? pk_[1] : pk_[3], 32);
    const unsigned x2 = __shfl_xor(hi ? pk_[4] : pk_[6], 32);
    const unsigned x3 = __shfl_xor(hi ? pk_[5] : pk_[7], 32);
    u32x4 f0, f1;
    f0[0] = hi ? x0 : pk_[0]; f0[1] = hi ? x1 : pk_[1];
    f0[2] = hi ? pk_[2] : x0; f0[3] = hi ? pk_[3] : x1;
    f1[0] = hi ? x2 : pk_[4]; f1[1] = hi ? x3 : pk_[5];
    f1[2] = hi ? pk_[6] : x2; f1[3] = hi ? pk_[7] : x3;
    const bf16x8 pf0 = __builtin_bit_cast(bf16x8, f0);
    const bf16x8 pf1 = __builtin_bit_cast(bf16x8, f1);
    // PV: O^T[d][q] += V^T . P
#pragma unroll
    for (int dg = 0; dg < 4; ++dg){
      oacc[dg] = mfma32(vf[dg][0], pf0, oacc[dg]);
      oacc[dg] = mfma32(vf[dg][1], pf1, oacc[dg]);
    }
    __syncthreads();
  }

  // 2-way merge across key-parity wave pairs (overlay obuf on staging LDS)
  float* ob = (float*)smem;   // [2 q-tiles][32 q][132]
  if (p == 1){
    if (lane < 32){ stats[qt][0][l31] = m; stats[qt][1][l31] = l; }
#pragma unroll
    for (int dg = 0; dg < 4; ++dg)
#pragma unroll
      for (int rq = 0; rq < 4; ++rq){
        f32x4 v4;
#pragma unroll
        for (int j = 0; j < 4; ++j) v4[j] = oacc[dg][rq*4 + j];
        *(f32x4*)&ob[(qt*32 + l31)*132 + dg*32 + rq*8 + hi*4] = v4;
      }
  }
  __syncthreads();
  if (p == 0){
    const float m1 = stats[qt][0][l31], l1 = stats[qt][1][l31];
    const float mM = fmaxf(m, m1);
    const float c0 = __expf(m - mM), c1 = __expf(m1 - mM);
    const float inv = 1.0f / (c0*l + c1*l1);
#pragma unroll
    for (int dg = 0; dg < 4; ++dg)
#pragma unroll
      for (int rq = 0; rq < 4; ++rq){
        const f32x4 v1 = *(const f32x4*)&ob[(qt*32 + l31)*132 + dg*32 + rq*8 + hi*4];
        u16x4 h4;
#pragma unroll
        for (int j = 0; j < 4; ++j)
          h4[j] = f2bf((c0*oacc[dg][rq*4 + j] + c1*v1[j]) * inv);
        const int d0 = dg*32 + rq*8 + hi*4;
        *(u16x4*)&o[((size_t)(q0 + l31))*DD + h*HDIM + d0] = h4;
      }
  }
}

// ---------------- K5: output projection GEMM + bias + residual ----------------
__global__ __launch_bounds__(256) void k_gemm_out(
    const u16* __restrict__ A, const u16* __restrict__ B, const float* __restrict__ bias,
    const float* __restrict__ xn32, float* __restrict__ out)
{
  __shared__ __align__(16) u16 lds_a[128*32];
  __shared__ __align__(16) u16 lds_b[128*32];
  // bijective XCD swizzle: 256 blocks, each XCD gets 32 consecutive wg
  const int wg = (blockIdx.x & 7)*32 + (blockIdx.x >> 3);
  const int bm = wg & 15, bn = wg >> 4;
  f32x4 acc[4][4] = {};
  gemm_tile_128(A, B, DD, bm, bn, lds_a, lds_b, acc);
  const int t = threadIdx.x, lane = t & 63;
  const int wm = (t >> 6) >> 1, wn = (t >> 6) & 1;
  const int g = lane >> 4, r16 = lane & 15;
#pragma unroll
  for (int a = 0; a < 4; ++a){
#pragma unroll
    for (int b = 0; b < 4; ++b){
      const int n = bn*128 + wn*64 + b*16 + r16;
      const float bi = bias[n];
#pragma unroll
      for (int rr = 0; rr < 4; ++rr){
        const int s = bm*128 + wm*64 + a*16 + g*4 + rr;
        out[(size_t)s*DD + n] = acc[a][b][rr] + bi + xn32[(size_t)s*DD + n];
      }
    }
  }
}

extern "C" void kernel_launch(void* const* d_in, const int* in_sizes, int n_in,
                              void* d_out, int out_size, void* d_ws, size_t ws_size,
                              hipStream_t stream)
{
  (void)in_sizes; (void)n_in; (void)out_size; (void)ws_size;
  const float* br     = (const float*)d_in[0];
  const int*   cat    = (const int*)d_in[1];
  const int*   cse    = (const int*)d_in[2];
  const int*   cmb    = (const int*)d_in[3];
  const int*   seg    = (const int*)d_in[4];
  const float* cat_e  = (const float*)d_in[5];
  const float* case_e = (const float*)d_in[6];
  const float* comb_e = (const float*)d_in[7];
  const float* ln_g   = (const float*)d_in[8];
  const float* ln_b   = (const float*)d_in[9];
  const float* in_w   = (const float*)d_in[10];
  const float* in_b   = (const float*)d_in[11];
  const float* out_w  = (const float*)d_in[12];
  const float* out_b  = (const float*)d_in[13];
  float* out = (float*)d_out;

  char* ws = (char*)d_ws;
  float* xn32  = (float*)(ws);                     // 16 MiB
  u16*   xn16  = (u16*)(ws + 16777216);            // 8 MiB
  u16*   inw16 = (u16*)(ws + 25165824);            // 24 MiB
  u16*   outw16= (u16*)(ws + 50331648);            // 8 MiB
  u16*   qws   = (u16*)(ws + 58720256);            // 8 MiB  [H][S][hd], pre-scaled
  u16*   kws   = (u16*)(ws + 67108864);            // 8 MiB  [H][S][hd]
  u16*   vtws  = (u16*)(ws + 75497472);            // 8 MiB  [H][hd][S]
  u16*   ows   = (u16*)(ws + 83886080);            // 8 MiB  [S][D]

  k_embed_ln<<<SS, 256, 0, stream>>>(br, cat, cse, cmb, cat_e, case_e, comb_e,
                                     ln_g, ln_b, xn32, xn16);
  k_f32_to_bf16<<<2048, 256, 0, stream>>>(in_w, inw16, 3*DD*DD/4);
  k_f32_to_bf16<<<2048, 256, 0, stream>>>(out_w, outw16, DD*DD/4);
  k_gemm_qkv<<<768, 256, 0, stream>>>(xn16, inw16, in_b, qws, kws, vtws);
  k_attn<<<512, 256, 0, stream>>>(qws, kws, vtws, seg, ows);
  k_gemm_out<<<256, 256, 0, stream>>>(ows, outw16, out_b, xn32, out);
}

// Round 5
// 309.610 us; speedup vs baseline: 1.2923x; 1.0954x over previous
//
#include <hip/hip_runtime.h>
#include <hip/hip_bf16.h>

#define SS 2048
#define DD 2048
#define HH 16
#define HDIM 128

typedef unsigned short u16;
typedef __attribute__((ext_vector_type(8))) short bf16x8;
typedef __attribute__((ext_vector_type(4))) float f32x4;
typedef __attribute__((ext_vector_type(16))) float f32x16;
typedef __attribute__((ext_vector_type(4))) unsigned short u16x4;
typedef __attribute__((ext_vector_type(4))) int i32x4;
typedef __attribute__((ext_vector_type(4))) unsigned int u32x4;

__device__ __forceinline__ u16 f2bf(float f){
  unsigned u = __float_as_uint(f);
  u += 0x7FFFu + ((u >> 16) & 1u);
  return (u16)(u >> 16);
}

__device__ __forceinline__ void gload_lds16(const void* g, void* l){
  __builtin_amdgcn_global_load_lds(
      (const __attribute__((address_space(1))) void*)g,
      (__attribute__((address_space(3))) void*)l, 16, 0, 0);
}

__device__ __forceinline__ f32x4 mfma16(bf16x8 a, bf16x8 b, f32x4 c){
  return __builtin_amdgcn_mfma_f32_16x16x32_bf16(a, b, c, 0, 0, 0);
}
__device__ __forceinline__ f32x16 mfma32(bf16x8 a, bf16x8 b, f32x16 c){
  return __builtin_amdgcn_mfma_f32_32x32x16_bf16(a, b, c, 0, 0, 0);
}

// raw barrier with compiler memory fence (no implicit vmcnt(0) drain)
__device__ __forceinline__ void barf(){
  asm volatile("" ::: "memory");
  __builtin_amdgcn_s_barrier();
  asm volatile("" ::: "memory");
}
#define VMCNT2() asm volatile("s_waitcnt vmcnt(2)" ::: "memory")

// ---------------- K1: fused embedding add + LayerNorm ----------------
__global__ __launch_bounds__(256) void k_embed_ln(
    const float* __restrict__ br, const int* __restrict__ cat,
    const int* __restrict__ cse, const int* __restrict__ cmb,
    const float* __restrict__ cat_e, const float* __restrict__ case_e,
    const float* __restrict__ comb_e, const float* __restrict__ lg,
    const float* __restrict__ lb, float* __restrict__ xn32, u16* __restrict__ xn16)
{
  const int s = blockIdx.x, t = threadIdx.x;
  const int lane = t & 63, wave = t >> 6;
  const int c0 = cat[s], c1 = cse[s], c2 = cmb[s];
  const f32x4* pb = (const f32x4*)(br + (size_t)s * DD);
  const f32x4* e0 = (const f32x4*)(cat_e + (size_t)c0 * DD);
  const f32x4* e1 = (const f32x4*)(case_e + (size_t)c1 * DD);
  const f32x4* e2 = (const f32x4*)(comb_e + (size_t)c2 * DD);
  f32x4 xa = pb[t] + e0[t] + e1[t] + e2[t];
  f32x4 xb = pb[t+256] + e0[t+256] + e1[t+256] + e2[t+256];
  float s1 = 0.f, s2 = 0.f;
#pragma unroll
  for (int i = 0; i < 4; ++i){ s1 += xa[i] + xb[i]; s2 += xa[i]*xa[i] + xb[i]*xb[i]; }
#pragma unroll
  for (int off = 32; off > 0; off >>= 1){ s1 += __shfl_down(s1, off); s2 += __shfl_down(s2, off); }
  __shared__ float red[8];
  if (lane == 0){ red[wave*2] = s1; red[wave*2+1] = s2; }
  __syncthreads();
  const float t1 = red[0]+red[2]+red[4]+red[6];
  const float t2 = red[1]+red[3]+red[5]+red[7];
  const float mean = t1 * (1.0f/DD);
  const float var  = t2 * (1.0f/DD) - mean*mean;
  const float rstd = rsqrtf(var + 1e-5f);
  const f32x4* g4 = (const f32x4*)lg;
  const f32x4* b4 = (const f32x4*)lb;
  f32x4 ga = g4[t], gb = g4[t+256], ba = b4[t], bb = b4[t+256];
  f32x4 ya, yb; u16x4 ha, hb;
#pragma unroll
  for (int i = 0; i < 4; ++i){
    ya[i] = (xa[i]-mean)*rstd*ga[i] + ba[i];
    yb[i] = (xb[i]-mean)*rstd*gb[i] + bb[i];
    ha[i] = f2bf(ya[i]); hb[i] = f2bf(yb[i]);
  }
  ((f32x4*)(xn32 + (size_t)s*DD))[t]     = ya;
  ((f32x4*)(xn32 + (size_t)s*DD))[t+256] = yb;
  ((u16x4*)(xn16 + (size_t)s*DD))[t]     = ha;
  ((u16x4*)(xn16 + (size_t)s*DD))[t+256] = hb;
}

// ---------------- K2: f32 -> bf16 convert ----------------
__global__ __launch_bounds__(256) void k_f32_to_bf16(
    const float* __restrict__ in, u16* __restrict__ out, int n4)
{
  int i = blockIdx.x * blockDim.x + threadIdx.x;
  const int stride = gridDim.x * blockDim.x;
  for (; i < n4; i += stride){
    f32x4 v = ((const f32x4*)in)[i];
    u16x4 h;
#pragma unroll
    for (int j = 0; j < 4; ++j) h[j] = f2bf(v[j]);
    ((u16x4*)out)[i] = h;
  }
}

// ---------------- K3: QKV projection, 256x256 8-phase-style pipelined GEMM ----------------
// 512 threads = 8 waves (2M x 4N); per-wave C = 128x64 (acc[8][4]); BK=64.
// LDS: 2 K-tile buffers x 4 half-tiles [128][64] bf16, slot^=(row&7) swizzled.
// Counted vmcnt(2) once per K-tile; raw barriers; setprio around MFMA clusters.
__global__ __launch_bounds__(512) void k_gemm_qkv(
    const u16* __restrict__ A, const u16* __restrict__ B, const float* __restrict__ bias,
    u16* __restrict__ qws, u16* __restrict__ kws, u16* __restrict__ vtws)
{
  __shared__ __align__(16) u16 lds[2][4][128*64];
  const int bid = blockIdx.x;                 // 192 blocks, 24 per XCD
  const int wg = (bid & 7)*24 + (bid >> 3);
  const int bm = wg & 7, bn = wg >> 3;        // 8 x 24
  const int t = threadIdx.x, lane = t & 63, wid = t >> 6;
  const int wm = wid >> 2, wn = wid & 3;
  const int r16 = lane & 15, g = lane >> 4;
  const u16* Ab = A + (size_t)bm*256*DD;
  const u16* Bb = B + (size_t)bn*256*DD;

  f32x4 acc[8][4] = {};

  auto stage_half = [&](int buf, int kt, int hh){
    const u16* src = (hh < 2) ? Ab : Bb;
    const int rbase = (hh & 1) * 128;
    u16* dst = (u16*)&lds[buf][hh][0];
#pragma unroll
    for (int i = 0; i < 2; ++i){
      const int ci = i*512 + t;
      const int row = ci >> 3, slot = ci & 7;
      gload_lds16(src + (size_t)(rbase + row)*DD + kt*64 + ((slot ^ (row & 7))*8),
                  dst + ci*8);
    }
  };
  auto frag = [&](const u16* half, int row, int k32) -> bf16x8 {
    return *(const bf16x8*)((const char*)half + row*128 + (((k32*4 + g) ^ (row & 7))*16));
  };

  // prologue: K-tile0 fully, K-tile1 half0
  stage_half(0, 0, 0); stage_half(0, 0, 1); stage_half(0, 0, 2); stage_half(0, 0, 3);
  stage_half(1, 1, 0);
  VMCNT2();
  barf();

  const int rB0 = (wn & 1)*64 + r16;
  for (int kt = 0; kt < 32; ++kt){
    const int cur = kt & 1;
    const u16* bufA = &lds[cur][wm][0];
    const u16* bufB = &lds[cur][2 + (wn >> 1)][0];
    bf16x8 a0[4][2], a1[4][2], b0[2][2], b1[2][2];
    // ---- phase 1: quadrant (mq0,nq0) — 12 ds_reads
#pragma unroll
    for (int i = 0; i < 4; ++i){
      a0[i][0] = frag(bufA, i*16 + r16, 0);
      a0[i][1] = frag(bufA, i*16 + r16, 1);
    }
#pragma unroll
    for (int j = 0; j < 2; ++j){
      b0[j][0] = frag(bufB, rB0 + j*16, 0);
      b0[j][1] = frag(bufB, rB0 + j*16, 1);
    }
    if (kt + 1 < 32) stage_half(cur^1, kt+1, 1);
    barf();
    __builtin_amdgcn_s_setprio(1);
#pragma unroll
    for (int k = 0; k < 2; ++k)
#pragma unroll
      for (int i = 0; i < 4; ++i)
#pragma unroll
        for (int j = 0; j < 2; ++j)
          acc[i][j] = mfma16(a0[i][k], b0[j][k], acc[i][j]);
    __builtin_amdgcn_s_setprio(0);
    barf();
    // ---- phase 2: quadrant (mq0,nq1) — 4 ds_reads
#pragma unroll
    for (int j = 0; j < 2; ++j){
      b1[j][0] = frag(bufB, rB0 + (2+j)*16, 0);
      b1[j][1] = frag(bufB, rB0 + (2+j)*16, 1);
    }
    if (kt + 1 < 32) stage_half(cur^1, kt+1, 2);
    barf();
    __builtin_amdgcn_s_setprio(1);
#pragma unroll
    for (int k = 0; k < 2; ++k)
#pragma unroll
      for (int i = 0; i < 4; ++i)
#pragma unroll
        for (int j = 0; j < 2; ++j)
          acc[i][2+j] = mfma16(a0[i][k], b1[j][k], acc[i][2+j]);
    __builtin_amdgcn_s_setprio(0);
    barf();
    // ---- phase 3: quadrant (mq1,nq1) — 8 ds_reads (last reads of this buffer)
#pragma unroll
    for (int i = 0; i < 4; ++i){
      a1[i][0] = frag(bufA, (4+i)*16 + r16, 0);
      a1[i][1] = frag(bufA, (4+i)*16 + r16, 1);
    }
    if (kt + 1 < 32) stage_half(cur^1, kt+1, 3);
    barf();
    __builtin_amdgcn_s_setprio(1);
#pragma unroll
    for (int k = 0; k < 2; ++k)
#pragma unroll
      for (int i = 0; i < 4; ++i)
#pragma unroll
        for (int j = 0; j < 2; ++j)
          acc[4+i][2+j] = mfma16(a1[i][k], b1[j][k], acc[4+i][2+j]);
    __builtin_amdgcn_s_setprio(0);
    barf();
    // ---- phase 4: quadrant (mq1,nq0) — 0 ds_reads; safe to overwrite h0 of this buf
    if (kt + 2 < 32) stage_half(cur, kt+2, 0);
    barf();
    __builtin_amdgcn_s_setprio(1);
#pragma unroll
    for (int k = 0; k < 2; ++k)
#pragma unroll
      for (int i = 0; i < 4; ++i)
#pragma unroll
        for (int j = 0; j < 2; ++j)
          acc[4+i][j] = mfma16(a1[i][k], b0[j][k], acc[4+i][j]);
    __builtin_amdgcn_s_setprio(0);
    VMCNT2();   // kt+1 fully landed; only kt+2-h0 (2 loads) may remain in flight
    barf();
  }

  // epilogue: bias + scatter to q (scaled), k, v^T
  const float qscale = 0.08838834764831845f; // 1/sqrt(128)
  const int colb = bn*256 + wn*64;
  const int rowb = bm*256 + wm*128 + g*4;
#pragma unroll
  for (int n = 0; n < 4; ++n){
    const int col = colb + n*16 + r16;
    const int which = col >> 11;
    const int h = (col >> 7) & 15;
    const int hd = col & 127;
    const float bi = bias[col];
#pragma unroll
    for (int m = 0; m < 8; ++m){
      const int row0 = rowb + m*16;
      if (which == 0){
#pragma unroll
        for (int r = 0; r < 4; ++r)
          qws[((size_t)h*SS + row0 + r)*HDIM + hd] = f2bf((acc[m][n][r] + bi)*qscale);
      } else if (which == 1){
#pragma unroll
        for (int r = 0; r < 4; ++r)
          kws[((size_t)h*SS + row0 + r)*HDIM + hd] = f2bf(acc[m][n][r] + bi);
      } else {
        u16x4 pk;
#pragma unroll
        for (int r = 0; r < 4; ++r) pk[r] = f2bf(acc[m][n][r] + bi);
        *(u16x4*)&vtws[((size_t)h*HDIM + hd)*SS + row0] = pk;
      }
    }
  }
}

// ---------------- shared 128x128 bf16 MFMA main loop (m97 structure) ----------------
__device__ __forceinline__ void gemm_tile_128(
    const u16* A, const u16* B, int K, int bm, int bn,
    u16* lds_a, u16* lds_b, f32x4 acc[4][4])
{
  const int t = threadIdx.x;
  const int lane = t & 63;
  const int wm = (t >> 6) >> 1, wn = (t >> 6) & 1;
  const int g = lane >> 4, r16 = lane & 15;
  const u16* Ab = A + (size_t)bm * 128 * K;
  const u16* Bb = B + (size_t)bn * 128 * K;
  for (int kt = 0; kt < K; kt += 32){
#pragma unroll
    for (int half = 0; half < 2; ++half){
      const int tt = half*256 + t;
      const int row = tt >> 2, col = (tt & 3) * 8;
      gload_lds16(Ab + (size_t)row*K + kt + col, lds_a + tt*8);
      gload_lds16(Bb + (size_t)row*K + kt + col, lds_b + tt*8);
    }
    __syncthreads();
    bf16x8 af[4], bfr[4];
#pragma unroll
    for (int i = 0; i < 4; ++i){
      af[i]  = *(const bf16x8*)(lds_a + (wm*64 + i*16 + r16)*32 + g*8);
      bfr[i] = *(const bf16x8*)(lds_b + (wn*64 + i*16 + r16)*32 + g*8);
    }
#pragma unroll
    for (int a = 0; a < 4; ++a)
#pragma unroll
      for (int b = 0; b < 4; ++b)
        acc[a][b] = mfma16(af[a], bfr[b], acc[a][b]);
    __syncthreads();
  }
}

// ---------------- K4: flash attention, swapped-QK^T 32x32, 2 blocks/CU ----------------
__global__ __launch_bounds__(256, 2) void k_attn(
    const u16* __restrict__ q, const u16* __restrict__ kk_, const u16* __restrict__ vt,
    const int* __restrict__ seg, u16* __restrict__ o)
{
  __shared__ __align__(16) char smem[65536];
  __shared__ float stats[2][2][32];
  const int bid = blockIdx.x;
  const int xcd = bid & 7, ii = bid >> 3;
  const int h = xcd*2 + (ii >> 5), qb = ii & 31;
  const int t = threadIdx.x, lane = t & 63, w = t >> 6;
  const int hi = lane >> 5, l31 = lane & 31;
  const int p = w >> 1, qt = w & 1;
  const int q0 = qb*64 + qt*32;

  const char* khead  = (const char*)(kk_ + (size_t)h*SS*HDIM);
  const char* vthead = (const char*)(vt  + (size_t)h*HDIM*SS);

  bf16x8 qf[8];
  {
    const u16* qp = q + ((size_t)h*SS + q0 + l31)*HDIM + hi*8;
#pragma unroll
    for (int c = 0; c < 8; ++c) qf[c] = *(const bf16x8*)(qp + c*16);
  }
  const int seg_q = seg[q0 + l31];
  const int swz = l31 & 7;

  f32x16 oacc[4];
#pragma unroll
  for (int dg = 0; dg < 4; ++dg)
#pragma unroll
    for (int r = 0; r < 16; ++r) oacc[dg][r] = 0.f;
  float m = -1e30f, l = 0.f;

  auto stage = [&](int buf, int kb){
#pragma unroll
    for (int i = 0; i < 4; ++i){
      const int ci = i*256 + t;
      const int row = ci >> 4, slot = ci & 15;
      gload_lds16(khead + (size_t)(kb + row)*256 + ((slot ^ (row & 7))*16),
                  smem + buf*16384 + ci*16);
    }
#pragma unroll
    for (int i = 0; i < 4; ++i){
      const int ci = i*256 + t;
      const int row = ci >> 3, slot = ci & 7;
      gload_lds16(vthead + (size_t)row*(SS*2) + (size_t)kb*2 + ((slot ^ (row & 7))*16),
                  smem + 32768 + buf*16384 + ci*16);
    }
  };

  stage(0, 0);
  __syncthreads();

  for (int it = 0; it < 32; ++it){
    const int cur = it & 1;
    if (it < 31) stage(cur^1, (it+1)*64);

    bf16x8 kf[8];
    const char* kl = smem + cur*16384 + (p*32 + l31)*256;
#pragma unroll
    for (int c = 0; c < 8; ++c)
      kf[c] = *(const bf16x8*)(kl + (((2*c + hi) ^ swz)*16));
    const int kb_w = it*64 + p*32;
    i32x4 sg[4];
#pragma unroll
    for (int rq = 0; rq < 4; ++rq) sg[rq] = *(const i32x4*)(seg + kb_w + rq*8 + hi*4);
    bf16x8 vf[4][2];
#pragma unroll
    for (int dg = 0; dg < 4; ++dg){
      const char* vl = smem + 32768 + cur*16384 + (dg*32 + l31)*128;
#pragma unroll
      for (int ks = 0; ks < 2; ++ks)
        vf[dg][ks] = *(const bf16x8*)(vl + (((p*4 + 2*ks + hi) ^ swz)*16));
    }

    f32x16 se, so;
#pragma unroll
    for (int r = 0; r < 16; ++r){ se[r] = 0.f; so[r] = 0.f; }
#pragma unroll
    for (int c = 0; c < 4; ++c){
      se = mfma32(kf[2*c],   qf[2*c],   se);
      so = mfma32(kf[2*c+1], qf[2*c+1], so);
    }
    f32x16 s = se + so;

    float tm = -1e30f;
#pragma unroll
    for (int r = 0; r < 16; ++r){
      const int sk = sg[r>>2][r&3];
      s[r] += (sk == seg_q) ? 1.0f : 0.0f;
      tm = fmaxf(tm, s[r]);
    }
    tm = fmaxf(tm, __shfl_xor(tm, 32));
    if (!__all(tm <= m + 8.0f)){
      const float mn = fmaxf(m, tm);
      const float sc = __expf(m - mn);
      l *= sc;
#pragma unroll
      for (int dg = 0; dg < 4; ++dg)
#pragma unroll
        for (int r = 0; r < 16; ++r) oacc[dg][r] *= sc;
      m = mn;
    }
    float pr[16]; float ts = 0.f;
#pragma unroll
    for (int r = 0; r < 16; ++r){ pr[r] = __expf(s[r] - m); ts += pr[r]; }
    ts += __shfl_xor(ts, 32);
    l += ts;
    unsigned pk_[8];
#pragma unroll
    for (int i = 0; i < 8; ++i)
      pk_[i] = (unsigned)f2bf(pr[2*i]) | ((unsigned)f2bf(pr[2*i+1]) << 16);
    const unsigned x0 = __shfl_xor(hi ? pk_[0] : pk_[2], 32);
    const unsigned x1 = __shfl_xor(hi ? pk_[1] : pk_[3], 32);
    const unsigned x2 = __shfl_xor(hi ? pk_[4] : pk_[6], 32);
    const unsigned x3 = __shfl_xor(hi ? pk_[5] : pk_[7], 32);
    u32x4 f0, f1;
    f0[0] = hi ? x0 : pk_[0]; f0[1] = hi ? x1 : pk_[1];
    f0[2] = hi ? pk_[2] : x0; f0[3] = hi ? pk_[3] : x1;
    f1[0] = hi ? x2 : pk_[4]; f1[1] = hi ? x3 : pk_[5];
    f1[2] = hi ? pk_[6] : x2; f1[3] = hi ? pk_[7] : x3;
    const bf16x8 pf0 = __builtin_bit_cast(bf16x8, f0);
    const bf16x8 pf1 = __builtin_bit_cast(bf16x8, f1);
#pragma unroll
    for (int dg = 0; dg < 4; ++dg){
      oacc[dg] = mfma32(vf[dg][0], pf0, oacc[dg]);
      oacc[dg] = mfma32(vf[dg][1], pf1, oacc[dg]);
    }
    __syncthreads();
  }

  float* ob = (float*)smem;
  if (p == 1){
    if (lane < 32){ stats[qt][0][l31] = m; stats[qt][1][l31] = l; }
#pragma unroll
    for (int dg = 0; dg < 4; ++dg)
#pragma unroll
      for (int rq = 0; rq < 4; ++rq){
        f32x4 v4;
#pragma unroll
        for (int j = 0; j < 4; ++j) v4[j] = oacc[dg][rq*4 + j];
        *(f32x4*)&ob[(qt*32 + l31)*132 + dg*32 + rq*8 + hi*4] = v4;
      }
  }
  __syncthreads();
  if (p == 0){
    const float m1 = stats[qt][0][l31], l1 = stats[qt][1][l31];
    const float mM = fmaxf(m, m1);
    const float c0 = __expf(m - mM), c1 = __expf(m1 - mM);
    const float inv = 1.0f / (c0*l + c1*l1);
#pragma unroll
    for (int dg = 0; dg < 4; ++dg)
#pragma unroll
      for (int rq = 0; rq < 4; ++rq){
        const f32x4 v1 = *(const f32x4*)&ob[(qt*32 + l31)*132 + dg*32 + rq*8 + hi*4];
        u16x4 h4;
#pragma unroll
        for (int j = 0; j < 4; ++j)
          h4[j] = f2bf((c0*oacc[dg][rq*4 + j] + c1*v1[j]) * inv);
        const int d0 = dg*32 + rq*8 + hi*4;
        *(u16x4*)&o[((size_t)(q0 + l31))*DD + h*HDIM + d0] = h4;
      }
  }
}

// ---------------- K5: output projection GEMM + bias + residual ----------------
__global__ __launch_bounds__(256) void k_gemm_out(
    const u16* __restrict__ A, const u16* __restrict__ B, const float* __restrict__ bias,
    const float* __restrict__ xn32, float* __restrict__ out)
{
  __shared__ __align__(16) u16 lds_a[128*32];
  __shared__ __align__(16) u16 lds_b[128*32];
  const int wg = (blockIdx.x & 7)*32 + (blockIdx.x >> 3);
  const int bm = wg & 15, bn = wg >> 4;
  f32x4 acc[4][4] = {};
  gemm_tile_128(A, B, DD, bm, bn, lds_a, lds_b, acc);
  const int t = threadIdx.x, lane = t & 63;
  const int wm = (t >> 6) >> 1, wn = (t >> 6) & 1;
  const int g = lane >> 4, r16 = lane & 15;
#pragma unroll
  for (int a = 0; a < 4; ++a){
#pragma unroll
    for (int b = 0; b < 4; ++b){
      const int n = bn*128 + wn*64 + b*16 + r16;
      const float bi = bias[n];
#pragma unroll
      for (int rr = 0; rr < 4; ++rr){
        const int s = bm*128 + wm*64 + a*16 + g*4 + rr;
        out[(size_t)s*DD + n] = acc[a][b][rr] + bi + xn32[(size_t)s*DD + n];
      }
    }
  }
}

extern "C" void kernel_launch(void* const* d_in, const int* in_sizes, int n_in,
                              void* d_out, int out_size, void* d_ws, size_t ws_size,
                              hipStream_t stream)
{
  (void)in_sizes; (void)n_in; (void)out_size; (void)ws_size;
  const float* br     = (const float*)d_in[0];
  const int*   cat    = (const int*)d_in[1];
  const int*   cse    = (const int*)d_in[2];
  const int*   cmb    = (const int*)d_in[3];
  const int*   seg    = (const int*)d_in[4];
  const float* cat_e  = (const float*)d_in[5];
  const float* case_e = (const float*)d_in[6];
  const float* comb_e = (const float*)d_in[7];
  const float* ln_g   = (const float*)d_in[8];
  const float* ln_b   = (const float*)d_in[9];
  const float* in_w   = (const float*)d_in[10];
  const float* in_b   = (const float*)d_in[11];
  const float* out_w  = (const float*)d_in[12];
  const float* out_b  = (const float*)d_in[13];
  float* out = (float*)d_out;

  char* ws = (char*)d_ws;
  float* xn32  = (float*)(ws);                     // 16 MiB
  u16*   xn16  = (u16*)(ws + 16777216);            // 8 MiB
  u16*   inw16 = (u16*)(ws + 25165824);            // 24 MiB
  u16*   outw16= (u16*)(ws + 50331648);            // 8 MiB
  u16*   qws   = (u16*)(ws + 58720256);            // 8 MiB  [H][S][hd], pre-scaled
  u16*   kws   = (u16*)(ws + 67108864);            // 8 MiB  [H][S][hd]
  u16*   vtws  = (u16*)(ws + 75497472);            // 8 MiB  [H][hd][S]
  u16*   ows   = (u16*)(ws + 83886080);            // 8 MiB  [S][D]

  k_embed_ln<<<SS, 256, 0, stream>>>(br, cat, cse, cmb, cat_e, case_e, comb_e,
                                     ln_g, ln_b, xn32, xn16);
  k_f32_to_bf16<<<2048, 256, 0, stream>>>(in_w, inw16, 3*DD*DD/4);
  k_f32_to_bf16<<<2048, 256, 0, stream>>>(out_w, outw16, DD*DD/4);
  k_gemm_qkv<<<192, 512, 0, stream>>>(xn16, inw16, in_b, qws, kws, vtws);
  k_attn<<<512, 256, 0, stream>>>(qws, kws, vtws, seg, ows);
  k_gemm_out<<<256, 256, 0, stream>>>(ows, outw16, out_b, xn32, out);
}

// Round 6
// 299.145 us; speedup vs baseline: 1.3375x; 1.0350x over previous
//
#include <hip/hip_runtime.h>
#include <hip/hip_bf16.h>

#define SS 2048
#define DD 2048
#define HH 16
#define HDIM 128

typedef unsigned short u16;
typedef __attribute__((ext_vector_type(8))) short bf16x8;
typedef __attribute__((ext_vector_type(4))) float f32x4;
typedef __attribute__((ext_vector_type(16))) float f32x16;
typedef __attribute__((ext_vector_type(4))) unsigned short u16x4;
typedef __attribute__((ext_vector_type(4))) int i32x4;
typedef __attribute__((ext_vector_type(4))) unsigned int u32x4;

__device__ __forceinline__ u16 f2bf(float f){
  unsigned u = __float_as_uint(f);
  u += 0x7FFFu + ((u >> 16) & 1u);
  return (u16)(u >> 16);
}

__device__ __forceinline__ void gload_lds16(const void* g, void* l){
  __builtin_amdgcn_global_load_lds(
      (const __attribute__((address_space(1))) void*)g,
      (__attribute__((address_space(3))) void*)l, 16, 0, 0);
}

__device__ __forceinline__ f32x4 mfma16(bf16x8 a, bf16x8 b, f32x4 c){
  return __builtin_amdgcn_mfma_f32_16x16x32_bf16(a, b, c, 0, 0, 0);
}
__device__ __forceinline__ f32x16 mfma32(bf16x8 a, bf16x8 b, f32x16 c){
  return __builtin_amdgcn_mfma_f32_32x32x16_bf16(a, b, c, 0, 0, 0);
}

// raw barrier with compiler memory fence (no implicit vmcnt(0) drain)
__device__ __forceinline__ void barf(){
  asm volatile("" ::: "memory");
  __builtin_amdgcn_s_barrier();
  asm volatile("" ::: "memory");
}
#define VMCNT2() asm volatile("s_waitcnt vmcnt(2)" ::: "memory")

// ---------------- K1: fused embedding add + LayerNorm ----------------
__global__ __launch_bounds__(256) void k_embed_ln(
    const float* __restrict__ br, const int* __restrict__ cat,
    const int* __restrict__ cse, const int* __restrict__ cmb,
    const float* __restrict__ cat_e, const float* __restrict__ case_e,
    const float* __restrict__ comb_e, const float* __restrict__ lg,
    const float* __restrict__ lb, float* __restrict__ xn32, u16* __restrict__ xn16)
{
  const int s = blockIdx.x, t = threadIdx.x;
  const int lane = t & 63, wave = t >> 6;
  const int c0 = cat[s], c1 = cse[s], c2 = cmb[s];
  const f32x4* pb = (const f32x4*)(br + (size_t)s * DD);
  const f32x4* e0 = (const f32x4*)(cat_e + (size_t)c0 * DD);
  const f32x4* e1 = (const f32x4*)(case_e + (size_t)c1 * DD);
  const f32x4* e2 = (const f32x4*)(comb_e + (size_t)c2 * DD);
  f32x4 xa = pb[t] + e0[t] + e1[t] + e2[t];
  f32x4 xb = pb[t+256] + e0[t+256] + e1[t+256] + e2[t+256];
  float s1 = 0.f, s2 = 0.f;
#pragma unroll
  for (int i = 0; i < 4; ++i){ s1 += xa[i] + xb[i]; s2 += xa[i]*xa[i] + xb[i]*xb[i]; }
#pragma unroll
  for (int off = 32; off > 0; off >>= 1){ s1 += __shfl_down(s1, off); s2 += __shfl_down(s2, off); }
  __shared__ float red[8];
  if (lane == 0){ red[wave*2] = s1; red[wave*2+1] = s2; }
  __syncthreads();
  const float t1 = red[0]+red[2]+red[4]+red[6];
  const float t2 = red[1]+red[3]+red[5]+red[7];
  const float mean = t1 * (1.0f/DD);
  const float var  = t2 * (1.0f/DD) - mean*mean;
  const float rstd = rsqrtf(var + 1e-5f);
  const f32x4* g4 = (const f32x4*)lg;
  const f32x4* b4 = (const f32x4*)lb;
  f32x4 ga = g4[t], gb = g4[t+256], ba = b4[t], bb = b4[t+256];
  f32x4 ya, yb; u16x4 ha, hb;
#pragma unroll
  for (int i = 0; i < 4; ++i){
    ya[i] = (xa[i]-mean)*rstd*ga[i] + ba[i];
    yb[i] = (xb[i]-mean)*rstd*gb[i] + bb[i];
    ha[i] = f2bf(ya[i]); hb[i] = f2bf(yb[i]);
  }
  ((f32x4*)(xn32 + (size_t)s*DD))[t]     = ya;
  ((f32x4*)(xn32 + (size_t)s*DD))[t+256] = yb;
  ((u16x4*)(xn16 + (size_t)s*DD))[t]     = ha;
  ((u16x4*)(xn16 + (size_t)s*DD))[t+256] = hb;
}

// ---------------- K2: fused f32 -> bf16 convert of both weights ----------------
__global__ __launch_bounds__(256) void k_conv2(
    const float* __restrict__ a, const float* __restrict__ b,
    u16* __restrict__ oa, u16* __restrict__ ob, int n4a, int n4b)
{
  int i = blockIdx.x * blockDim.x + threadIdx.x;
  const int stride = gridDim.x * blockDim.x;
  const int n = n4a + n4b;
  for (; i < n; i += stride){
    f32x4 v;
    if (i < n4a) v = ((const f32x4*)a)[i];
    else         v = ((const f32x4*)b)[i - n4a];
    u16x4 h;
#pragma unroll
    for (int j = 0; j < 4; ++j) h[j] = f2bf(v[j]);
    if (i < n4a) ((u16x4*)oa)[i] = h;
    else         ((u16x4*)ob)[i - n4a] = h;
  }
}

// ---------------- K3: QKV projection, 256x256 8-phase pipelined GEMM ----------------
__global__ __launch_bounds__(512) void k_gemm_qkv(
    const u16* __restrict__ A, const u16* __restrict__ B, const float* __restrict__ bias,
    u16* __restrict__ qws, u16* __restrict__ kws, u16* __restrict__ vtws)
{
  __shared__ __align__(16) u16 lds[2][4][128*64];
  const int bid = blockIdx.x;                 // 192 blocks, 24 per XCD
  const int wg = (bid & 7)*24 + (bid >> 3);
  const int bm = wg & 7, bn = wg >> 3;        // 8 x 24
  const int t = threadIdx.x, lane = t & 63, wid = t >> 6;
  const int wm = wid >> 2, wn = wid & 3;
  const int r16 = lane & 15, g = lane >> 4;
  const u16* Ab = A + (size_t)bm*256*DD;
  const u16* Bb = B + (size_t)bn*256*DD;

  f32x4 acc[8][4] = {};

  auto stage_half = [&](int buf, int kt, int hh){
    const u16* src = (hh < 2) ? Ab : Bb;
    const int rbase = (hh & 1) * 128;
    u16* dst = (u16*)&lds[buf][hh][0];
#pragma unroll
    for (int i = 0; i < 2; ++i){
      const int ci = i*512 + t;
      const int row = ci >> 3, slot = ci & 7;
      gload_lds16(src + (size_t)(rbase + row)*DD + kt*64 + ((slot ^ (row & 7))*8),
                  dst + ci*8);
    }
  };
  auto frag = [&](const u16* half, int row, int k32) -> bf16x8 {
    return *(const bf16x8*)((const char*)half + row*128 + (((k32*4 + g) ^ (row & 7))*16));
  };

  stage_half(0, 0, 0); stage_half(0, 0, 1); stage_half(0, 0, 2); stage_half(0, 0, 3);
  stage_half(1, 1, 0);
  VMCNT2();
  barf();

  const int rB0 = (wn & 1)*64 + r16;
  for (int kt = 0; kt < 32; ++kt){
    const int cur = kt & 1;
    const u16* bufA = &lds[cur][wm][0];
    const u16* bufB = &lds[cur][2 + (wn >> 1)][0];
    bf16x8 a0[4][2], a1[4][2], b0[2][2], b1[2][2];
#pragma unroll
    for (int i = 0; i < 4; ++i){
      a0[i][0] = frag(bufA, i*16 + r16, 0);
      a0[i][1] = frag(bufA, i*16 + r16, 1);
    }
#pragma unroll
    for (int j = 0; j < 2; ++j){
      b0[j][0] = frag(bufB, rB0 + j*16, 0);
      b0[j][1] = frag(bufB, rB0 + j*16, 1);
    }
    if (kt + 1 < 32) stage_half(cur^1, kt+1, 1);
    barf();
    __builtin_amdgcn_s_setprio(1);
#pragma unroll
    for (int k = 0; k < 2; ++k)
#pragma unroll
      for (int i = 0; i < 4; ++i)
#pragma unroll
        for (int j = 0; j < 2; ++j)
          acc[i][j] = mfma16(a0[i][k], b0[j][k], acc[i][j]);
    __builtin_amdgcn_s_setprio(0);
    barf();
#pragma unroll
    for (int j = 0; j < 2; ++j){
      b1[j][0] = frag(bufB, rB0 + (2+j)*16, 0);
      b1[j][1] = frag(bufB, rB0 + (2+j)*16, 1);
    }
    if (kt + 1 < 32) stage_half(cur^1, kt+1, 2);
    barf();
    __builtin_amdgcn_s_setprio(1);
#pragma unroll
    for (int k = 0; k < 2; ++k)
#pragma unroll
      for (int i = 0; i < 4; ++i)
#pragma unroll
        for (int j = 0; j < 2; ++j)
          acc[i][2+j] = mfma16(a0[i][k], b1[j][k], acc[i][2+j]);
    __builtin_amdgcn_s_setprio(0);
    barf();
#pragma unroll
    for (int i = 0; i < 4; ++i){
      a1[i][0] = frag(bufA, (4+i)*16 + r16, 0);
      a1[i][1] = frag(bufA, (4+i)*16 + r16, 1);
    }
    if (kt + 1 < 32) stage_half(cur^1, kt+1, 3);
    barf();
    __builtin_amdgcn_s_setprio(1);
#pragma unroll
    for (int k = 0; k < 2; ++k)
#pragma unroll
      for (int i = 0; i < 4; ++i)
#pragma unroll
        for (int j = 0; j < 2; ++j)
          acc[4+i][2+j] = mfma16(a1[i][k], b1[j][k], acc[4+i][2+j]);
    __builtin_amdgcn_s_setprio(0);
    barf();
    if (kt + 2 < 32) stage_half(cur, kt+2, 0);
    barf();
    __builtin_amdgcn_s_setprio(1);
#pragma unroll
    for (int k = 0; k < 2; ++k)
#pragma unroll
      for (int i = 0; i < 4; ++i)
#pragma unroll
        for (int j = 0; j < 2; ++j)
          acc[4+i][j] = mfma16(a1[i][k], b0[j][k], acc[4+i][j]);
    __builtin_amdgcn_s_setprio(0);
    VMCNT2();
    barf();
  }

  const float qscale = 0.08838834764831845f; // 1/sqrt(128)
  const int colb = bn*256 + wn*64;
  const int rowb = bm*256 + wm*128 + g*4;
#pragma unroll
  for (int n = 0; n < 4; ++n){
    const int col = colb + n*16 + r16;
    const int which = col >> 11;
    const int h = (col >> 7) & 15;
    const int hd = col & 127;
    const float bi = bias[col];
#pragma unroll
    for (int m = 0; m < 8; ++m){
      const int row0 = rowb + m*16;
      if (which == 0){
#pragma unroll
        for (int r = 0; r < 4; ++r)
          qws[((size_t)h*SS + row0 + r)*HDIM + hd] = f2bf((acc[m][n][r] + bi)*qscale);
      } else if (which == 1){
#pragma unroll
        for (int r = 0; r < 4; ++r)
          kws[((size_t)h*SS + row0 + r)*HDIM + hd] = f2bf(acc[m][n][r] + bi);
      } else {
        u16x4 pk;
#pragma unroll
        for (int r = 0; r < 4; ++r) pk[r] = f2bf(acc[m][n][r] + bi);
        *(u16x4*)&vtws[((size_t)h*HDIM + hd)*SS + row0] = pk;
      }
    }
  }
}

// ---------------- K4: flash attention, swapped-QK^T 32x32, 2 blocks/CU ----------------
__global__ __launch_bounds__(256, 2) void k_attn(
    const u16* __restrict__ q, const u16* __restrict__ kk_, const u16* __restrict__ vt,
    const int* __restrict__ seg, u16* __restrict__ o)
{
  __shared__ __align__(16) char smem[65536];
  __shared__ float stats[2][2][32];
  const int bid = blockIdx.x;
  const int xcd = bid & 7, ii = bid >> 3;
  const int h = xcd*2 + (ii >> 5), qb = ii & 31;
  const int t = threadIdx.x, lane = t & 63, w = t >> 6;
  const int hi = lane >> 5, l31 = lane & 31;
  const int p = w >> 1, qt = w & 1;
  const int q0 = qb*64 + qt*32;

  const char* khead  = (const char*)(kk_ + (size_t)h*SS*HDIM);
  const char* vthead = (const char*)(vt  + (size_t)h*HDIM*SS);

  bf16x8 qf[8];
  {
    const u16* qp = q + ((size_t)h*SS + q0 + l31)*HDIM + hi*8;
#pragma unroll
    for (int c = 0; c < 8; ++c) qf[c] = *(const bf16x8*)(qp + c*16);
  }
  const int seg_q = seg[q0 + l31];
  const int swz = l31 & 7;

  f32x16 oacc[4];
#pragma unroll
  for (int dg = 0; dg < 4; ++dg)
#pragma unroll
    for (int r = 0; r < 16; ++r) oacc[dg][r] = 0.f;
  float m = -1e30f, l = 0.f;

  auto stage = [&](int buf, int kb){
#pragma unroll
    for (int i = 0; i < 4; ++i){
      const int ci = i*256 + t;
      const int row = ci >> 4, slot = ci & 15;
      gload_lds16(khead + (size_t)(kb + row)*256 + ((slot ^ (row & 7))*16),
                  smem + buf*16384 + ci*16);
    }
#pragma unroll
    for (int i = 0; i < 4; ++i){
      const int ci = i*256 + t;
      const int row = ci >> 3, slot = ci & 7;
      gload_lds16(vthead + (size_t)row*(SS*2) + (size_t)kb*2 + ((slot ^ (row & 7))*16),
                  smem + 32768 + buf*16384 + ci*16);
    }
  };

  stage(0, 0);
  __syncthreads();

  for (int it = 0; it < 32; ++it){
    const int cur = it & 1;
    if (it < 31) stage(cur^1, (it+1)*64);

    bf16x8 kf[8];
    const char* kl = smem + cur*16384 + (p*32 + l31)*256;
#pragma unroll
    for (int c = 0; c < 8; ++c)
      kf[c] = *(const bf16x8*)(kl + (((2*c + hi) ^ swz)*16));
    const int kb_w = it*64 + p*32;
    i32x4 sg[4];
#pragma unroll
    for (int rq = 0; rq < 4; ++rq) sg[rq] = *(const i32x4*)(seg + kb_w + rq*8 + hi*4);
    bf16x8 vf[4][2];
#pragma unroll
    for (int dg = 0; dg < 4; ++dg){
      const char* vl = smem + 32768 + cur*16384 + (dg*32 + l31)*128;
#pragma unroll
      for (int ks = 0; ks < 2; ++ks)
        vf[dg][ks] = *(const bf16x8*)(vl + (((p*4 + 2*ks + hi) ^ swz)*16));
    }

    f32x16 se, so;
#pragma unroll
    for (int r = 0; r < 16; ++r){ se[r] = 0.f; so[r] = 0.f; }
    __builtin_amdgcn_s_setprio(1);
#pragma unroll
    for (int c = 0; c < 4; ++c){
      se = mfma32(kf[2*c],   qf[2*c],   se);
      so = mfma32(kf[2*c+1], qf[2*c+1], so);
    }
    __builtin_amdgcn_s_setprio(0);
    f32x16 s = se + so;

#pragma unroll
    for (int r = 0; r < 16; ++r){
      const int sk = sg[r>>2][r&3];
      s[r] += (sk == seg_q) ? 1.0f : 0.0f;
    }
    // tile max: depth-4 tree
    float mx0 = fmaxf(fmaxf(s[0],s[1]), fmaxf(s[2],s[3]));
    float mx1 = fmaxf(fmaxf(s[4],s[5]), fmaxf(s[6],s[7]));
    float mx2 = fmaxf(fmaxf(s[8],s[9]), fmaxf(s[10],s[11]));
    float mx3 = fmaxf(fmaxf(s[12],s[13]), fmaxf(s[14],s[15]));
    float tm = fmaxf(fmaxf(mx0,mx1), fmaxf(mx2,mx3));
    tm = fmaxf(tm, __shfl_xor(tm, 32));
    if (!__all(tm <= m + 8.0f)){
      const float mn = fmaxf(m, tm);
      const float sc = __expf(m - mn);
      l *= sc;
#pragma unroll
      for (int dg = 0; dg < 4; ++dg)
#pragma unroll
        for (int r = 0; r < 16; ++r) oacc[dg][r] *= sc;
      m = mn;
    }
    float pr[16];
#pragma unroll
    for (int r = 0; r < 16; ++r) pr[r] = __expf(s[r] - m);
    // sum: depth-4 tree
    float s0_ = (pr[0]+pr[1]) + (pr[2]+pr[3]);
    float s1_ = (pr[4]+pr[5]) + (pr[6]+pr[7]);
    float s2_ = (pr[8]+pr[9]) + (pr[10]+pr[11]);
    float s3_ = (pr[12]+pr[13]) + (pr[14]+pr[15]);
    float ts = (s0_+s1_) + (s2_+s3_);
    ts += __shfl_xor(ts, 32);
    l += ts;
    unsigned pk_[8];
#pragma unroll
    for (int i = 0; i < 8; ++i)
      pk_[i] = (unsigned)f2bf(pr[2*i]) | ((unsigned)f2bf(pr[2*i+1]) << 16);
    const unsigned x0 = __shfl_xor(hi ? pk_[0] : pk_[2], 32);
    const unsigned x1 = __shfl_xor(hi ? pk_[1] : pk_[3], 32);
    const unsigned x2 = __shfl_xor(hi ? pk_[4] : pk_[6], 32);
    const unsigned x3 = __shfl_xor(hi ? pk_[5] : pk_[7], 32);
    u32x4 f0, f1;
    f0[0] = hi ? x0 : pk_[0]; f0[1] = hi ? x1 : pk_[1];
    f0[2] = hi ? pk_[2] : x0; f0[3] = hi ? pk_[3] : x1;
    f1[0] = hi ? x2 : pk_[4]; f1[1] = hi ? x3 : pk_[5];
    f1[2] = hi ? pk_[6] : x2; f1[3] = hi ? pk_[7] : x3;
    const bf16x8 pf0 = __builtin_bit_cast(bf16x8, f0);
    const bf16x8 pf1 = __builtin_bit_cast(bf16x8, f1);
    __builtin_amdgcn_s_setprio(1);
#pragma unroll
    for (int dg = 0; dg < 4; ++dg){
      oacc[dg] = mfma32(vf[dg][0], pf0, oacc[dg]);
      oacc[dg] = mfma32(vf[dg][1], pf1, oacc[dg]);
    }
    __builtin_amdgcn_s_setprio(0);
    __syncthreads();
  }

  float* ob = (float*)smem;
  if (p == 1){
    if (lane < 32){ stats[qt][0][l31] = m; stats[qt][1][l31] = l; }
#pragma unroll
    for (int dg = 0; dg < 4; ++dg)
#pragma unroll
      for (int rq = 0; rq < 4; ++rq){
        f32x4 v4;
#pragma unroll
        for (int j = 0; j < 4; ++j) v4[j] = oacc[dg][rq*4 + j];
        *(f32x4*)&ob[(qt*32 + l31)*132 + dg*32 + rq*8 + hi*4] = v4;
      }
  }
  __syncthreads();
  if (p == 0){
    const float m1 = stats[qt][0][l31], l1 = stats[qt][1][l31];
    const float mM = fmaxf(m, m1);
    const float c0 = __expf(m - mM), c1 = __expf(m1 - mM);
    const float inv = 1.0f / (c0*l + c1*l1);
#pragma unroll
    for (int dg = 0; dg < 4; ++dg)
#pragma unroll
      for (int rq = 0; rq < 4; ++rq){
        const f32x4 v1 = *(const f32x4*)&ob[(qt*32 + l31)*132 + dg*32 + rq*8 + hi*4];
        u16x4 h4;
#pragma unroll
        for (int j = 0; j < 4; ++j)
          h4[j] = f2bf((c0*oacc[dg][rq*4 + j] + c1*v1[j]) * inv);
        const int d0 = dg*32 + rq*8 + hi*4;
        *(u16x4*)&o[((size_t)(q0 + l31))*DD + h*HDIM + d0] = h4;
      }
  }
}

// ---------------- K5: output projection GEMM + bias + residual ----------------
// 128x64 tiles, grid 512 (2-3 blocks/CU), BK=64 dbuf swizzled LDS, 1 barrier/K-step.
__global__ __launch_bounds__(256, 3) void k_gemm_out(
    const u16* __restrict__ A, const u16* __restrict__ B, const float* __restrict__ bias,
    const float* __restrict__ xn32, float* __restrict__ out)
{
  __shared__ __align__(16) u16 ldsA[2][128*64];
  __shared__ __align__(16) u16 ldsB[2][64*64];
  const int bid = blockIdx.x;                 // 512 blocks, 64 per XCD
  const int wg = (bid & 7)*64 + (bid >> 3);
  const int bm = wg >> 5, bn = wg & 31;       // 16 x 32
  const int t = threadIdx.x, lane = t & 63, wid = t >> 6;
  const int wm = wid >> 1, wn = wid & 1;
  const int r16 = lane & 15, g = lane >> 4;
  const u16* Ab = A + (size_t)bm*128*DD;
  const u16* Bb = B + (size_t)bn*64*DD;

  f32x4 acc[4][2] = {};

  auto stage = [&](int buf, int kt){
#pragma unroll
    for (int i = 0; i < 4; ++i){
      const int ci = i*256 + t;
      const int row = ci >> 3, slot = ci & 7;
      gload_lds16(Ab + (size_t)row*DD + kt*64 + ((slot ^ (row & 7))*8),
                  ldsA[buf] + ci*8);
    }
#pragma unroll
    for (int i = 0; i < 2; ++i){
      const int ci = i*256 + t;
      const int row = ci >> 3, slot = ci & 7;
      gload_lds16(Bb + (size_t)row*DD + kt*64 + ((slot ^ (row & 7))*8),
                  ldsB[buf] + ci*8);
    }
  };
  auto frag = [&](const u16* half, int row, int k32) -> bf16x8 {
    return *(const bf16x8*)((const char*)half + row*128 + (((k32*4 + g) ^ (row & 7))*16));
  };

  stage(0, 0);
  __syncthreads();

  for (int kt = 0; kt < 32; ++kt){
    const int cur = kt & 1;
    if (kt + 1 < 32) stage(cur^1, kt+1);
    bf16x8 af[4][2], bfr[2][2];
#pragma unroll
    for (int i = 0; i < 4; ++i){
      af[i][0] = frag(ldsA[cur], wm*64 + i*16 + r16, 0);
      af[i][1] = frag(ldsA[cur], wm*64 + i*16 + r16, 1);
    }
#pragma unroll
    for (int j = 0; j < 2; ++j){
      bfr[j][0] = frag(ldsB[cur], wn*32 + j*16 + r16, 0);
      bfr[j][1] = frag(ldsB[cur], wn*32 + j*16 + r16, 1);
    }
    __builtin_amdgcn_s_setprio(1);
#pragma unroll
    for (int k = 0; k < 2; ++k)
#pragma unroll
      for (int i = 0; i < 4; ++i)
#pragma unroll
        for (int j = 0; j < 2; ++j)
          acc[i][j] = mfma16(af[i][k], bfr[j][k], acc[i][j]);
    __builtin_amdgcn_s_setprio(0);
    __syncthreads();
  }

#pragma unroll
  for (int i = 0; i < 4; ++i){
#pragma unroll
    for (int j = 0; j < 2; ++j){
      const int n = bn*64 + wn*32 + j*16 + r16;
      const float bi = bias[n];
#pragma unroll
      for (int r = 0; r < 4; ++r){
        const int s = bm*128 + wm*64 + i*16 + g*4 + r;
        out[(size_t)s*DD + n] = acc[i][j][r] + bi + xn32[(size_t)s*DD + n];
      }
    }
  }
}

extern "C" void kernel_launch(void* const* d_in, const int* in_sizes, int n_in,
                              void* d_out, int out_size, void* d_ws, size_t ws_size,
                              hipStream_t stream)
{
  (void)in_sizes; (void)n_in; (void)out_size; (void)ws_size;
  const float* br     = (const float*)d_in[0];
  const int*   cat    = (const int*)d_in[1];
  const int*   cse    = (const int*)d_in[2];
  const int*   cmb    = (const int*)d_in[3];
  const int*   seg    = (const int*)d_in[4];
  const float* cat_e  = (const float*)d_in[5];
  const float* case_e = (const float*)d_in[6];
  const float* comb_e = (const float*)d_in[7];
  const float* ln_g   = (const float*)d_in[8];
  const float* ln_b   = (const float*)d_in[9];
  const float* in_w   = (const float*)d_in[10];
  const float* in_b   = (const float*)d_in[11];
  const float* out_w  = (const float*)d_in[12];
  const float* out_b  = (const float*)d_in[13];
  float* out = (float*)d_out;

  char* ws = (char*)d_ws;
  float* xn32  = (float*)(ws);                     // 16 MiB
  u16*   xn16  = (u16*)(ws + 16777216);            // 8 MiB
  u16*   inw16 = (u16*)(ws + 25165824);            // 24 MiB
  u16*   outw16= (u16*)(ws + 50331648);            // 8 MiB
  u16*   qws   = (u16*)(ws + 58720256);            // 8 MiB  [H][S][hd], pre-scaled
  u16*   kws   = (u16*)(ws + 67108864);            // 8 MiB  [H][S][hd]
  u16*   vtws  = (u16*)(ws + 75497472);            // 8 MiB  [H][hd][S]
  u16*   ows   = (u16*)(ws + 83886080);            // 8 MiB  [S][D]

  k_embed_ln<<<SS, 256, 0, stream>>>(br, cat, cse, cmb, cat_e, case_e, comb_e,
                                     ln_g, ln_b, xn32, xn16);
  k_conv2<<<2048, 256, 0, stream>>>(in_w, out_w, inw16, outw16,
                                    3*DD*DD/4, DD*DD/4);
  k_gemm_qkv<<<192, 512, 0, stream>>>(xn16, inw16, in_b, qws, kws, vtws);
  k_attn<<<512, 256, 0, stream>>>(qws, kws, vtws, seg, ows);
  k_gemm_out<<<512, 256, 0, stream>>>(ows, outw16, out_b, xn32, out);
}